// Round 9
// baseline (165.196 us; speedup 1.0000x reference)
//
#include <hip/hip_runtime.h>
#include <math.h>

// SpaTrans on MI355X. R19b: single-pass in-place transpose in k_tok_qkv.
// (R19 failed to compile: gather locals g0/g1 shadowed the g1 kernel param.
//  Renamed to gt0/gt1; logic identical.)
//  * R18 post-mortem: prefetches real but small (-1.7us). The remaining
//    serial structure is the prologue: 3 rounds of {pack, barrier, LDS
//    read, write, barrier} = 6 barriers + 3 exposed LDS latencies before
//    the first MFMA.
//  * R19: stage all 3 rows UNTRANSPOSED into At/As_ themselves
//    ([dy][ch][34], 13.1KB < 14.7KB), one barrier, gather 48 transposed
//    ushorts into REGISTERS (reads pipelined across rows), one barrier,
//    write final layout in-place. 7 barriers -> 3. Invalid rows become
//    register zeros. LDS total unchanged -> 4 blocks/CU holds.
//  * k_attn_ffn (R17 de-spilled) / k_prep frozen.
//    Tripwire: WRITE_SIZE stays 25600KB (spill shows here first).
#define Lh 32
#define Lw 32
#define LL 1024
#define BN 25
#define EE 128
#define CC 64
#define NHD 8
#define DH 16
#define FFD 256
#define MROWS 25600

typedef __attribute__((ext_vector_type(8))) short short8;
typedef __attribute__((ext_vector_type(4))) float f32x4;

__device__ inline ushort f2b(float x) {
    union { float f; unsigned u; } v; v.f = x;
    unsigned r = (v.u + 0x7fffu + ((v.u >> 16) & 1u)) >> 16;
    return (ushort)r;
}
__device__ inline float b2f(ushort u) {
    union { unsigned u; float f; } v; v.u = ((unsigned)u) << 16;
    return v.f;
}

// ---------------------------------------------------------------------------
// Weight layout (ushorts). W2 K-reordered (k'=tap*64+ch). WO/W2F/WC k-PERMUTED
// (kpos=c*32+q*8+i <-> orig k=(2c+(i>>2))*16+q*4+(i&3)). Q rows pre-scaled 0.25.
// ---------------------------------------------------------------------------
#define OFF_W2  0
#define OFF_WQK 73728
#define OFF_WV  106496
#define OFF_WO  122880
#define OFF_W1  139264
#define OFF_W2F 172032
#define OFF_WC  204800
#define W_TOTAL 212992

__global__ __launch_bounds__(256) void k_prep(
    const float* __restrict__ w_mlp, const float* __restrict__ in_proj,
    const float* __restrict__ out_proj, const float* __restrict__ ff_w1,
    const float* __restrict__ ff_w2, const float* __restrict__ conv_w,
    ushort* __restrict__ Wb)
{
    int i = blockIdx.x * 256 + threadIdx.x;
    if (i >= W_TOTAL) return;
    if (i < 73728) {
        int e = i / 576, k = i - e * 576;
        int tap = k >> 6, ch = k & 63;
        Wb[OFF_W2 + i] = f2b(w_mlp[e * 576 + ch * 9 + tap]);
        return;
    }
    i -= 73728;
    if (i < 32768) {   // WQK; Q rows pre-scaled by 1/sqrt(16)
        float v = in_proj[i];
        Wb[OFF_WQK + i] = f2b(i < 16384 ? v * 0.25f : v);
        return;
    }
    i -= 32768;
    if (i < 16384) { Wb[OFF_WV + i] = f2b(in_proj[32768 + i]); return; }
    i -= 16384;
    if (i < 16384) {   // WO, k-permuted (K=128)
        int e = i >> 7, kpos = i & 127;
        int c = kpos >> 5, q = (kpos >> 3) & 3, ii = kpos & 7;
        int orig = (2 * c + (ii >> 2)) * 16 + q * 4 + (ii & 3);
        Wb[OFF_WO + i] = f2b(out_proj[e * 128 + orig]);
        return;
    }
    i -= 16384;
    if (i < 32768) { Wb[OFF_W1 + i] = f2b(ff_w1[i]); return; }
    i -= 32768;
    if (i < 32768) {   // W2F, k-permuted (K=256)
        int e = i >> 8, kpos = i & 255;
        int c = kpos >> 5, q = (kpos >> 3) & 3, ii = kpos & 7;
        int orig = (2 * c + (ii >> 2)) * 16 + q * 4 + (ii & 3);
        Wb[OFF_W2F + i] = f2b(ff_w2[e * 256 + orig]);
        return;
    }
    i -= 32768;
    {                  // WC, k-permuted (K=128)
        int o = i >> 7, kpos = i & 127;
        int c = kpos >> 5, q = (kpos >> 3) & 3, ii = kpos & 7;
        int orig = (2 * c + (ii >> 2)) * 16 + q * 4 + (ii & 3);
        Wb[OFF_WC + i] = f2b(conv_w[o * 128 + orig]);
    }
}

// ---------------------------------------------------------------------------
// Token embed + LN1 + QKV, input transpose fused. Grid 800.
// R16: LDS 39.1KB -> 4 blocks/CU, single generation.
// R18: tap-0 W2 prefetch; phase-B av prefetch.
// R19: single-pass in-place transpose (3 barriers, regs as pivot).
// ---------------------------------------------------------------------------
__global__ __launch_bounds__(256, 4) void k_tok_qkv(
    const float* __restrict__ buf, const float* __restrict__ spa,
    const ushort* __restrict__ W2, const ushort* __restrict__ WQK,
    const ushort* __restrict__ WV, const float* __restrict__ g1,
    const float* __restrict__ b1, ushort* __restrict__ TOKb,
    ushort* __restrict__ Qh, ushort* __restrict__ Kh, ushort* __restrict__ VTg)
{
    const int bid = blockIdx.x;                       // 800 blocks
    const int idx = (bid & 7) * 100 + (bid >> 3);     // XCD-contiguous chunks
    const int n = idx / 32, y = idx & 31;
    __shared__ ushort At[3 * 34 * 72];
    __shared__ ushort As_[3 * 34 * 72];
    __shared__ ushort VsBuf[32 * 136];
    __shared__ float2 red[32][4];
    ushort* Xs  = As_;               // alias: As_ dead after tap loop
    ushort* Vs  = VsBuf;
    const int t = threadIdx.x;
    const int w = t >> 6, lane = t & 63;
    const int col = lane & 15, quad = lane >> 4;
    const uint4 z = make_uint4(0, 0, 0, 0);

    // ---- R19 phase 1: load all 3 rows, pack bf16, stage UNTRANSPOSED
    // into At/As_ ([dy][ch][stride 34]; 13056B < 14688B region) ----
    {
        const int ch = t >> 2, x8 = (t & 3) * 8;
#pragma unroll
        for (int dy = 0; dy < 3; dy++) {
            int yy = y + dy - 1;
            if (yy >= 0 && yy < Lh) {
                const float* p = buf + ((size_t)(ch * BN + n) * LL + yy * Lw + x8);
                const float* q = spa + ((size_t)(ch * BN + n) * LL + yy * Lw + x8);
                float4 a0 = ((const float4*)p)[0], a1 = ((const float4*)p)[1];
                float4 b0 = ((const float4*)q)[0], b1 = ((const float4*)q)[1];
                union { ushort u[8]; uint w4[4]; } o0, o1;
                o0.u[0] = f2b(a0.x); o0.u[1] = f2b(a0.y); o0.u[2] = f2b(a0.z); o0.u[3] = f2b(a0.w);
                o0.u[4] = f2b(a1.x); o0.u[5] = f2b(a1.y); o0.u[6] = f2b(a1.z); o0.u[7] = f2b(a1.w);
                o1.u[0] = f2b(a0.x + b0.x); o1.u[1] = f2b(a0.y + b0.y);
                o1.u[2] = f2b(a0.z + b0.z); o1.u[3] = f2b(a0.w + b0.w);
                o1.u[4] = f2b(a1.x + b1.x); o1.u[5] = f2b(a1.y + b1.y);
                o1.u[6] = f2b(a1.z + b1.z); o1.u[7] = f2b(a1.w + b1.w);
                uint* d0 = (uint*)(At  + (dy * 64 + ch) * 34 + x8);
                uint* d1 = (uint*)(As_ + (dy * 64 + ch) * 34 + x8);
#pragma unroll
                for (int k = 0; k < 4; k++) { d0[k] = o0.w4[k]; d1[k] = o1.w4[k]; }
            }
        }
    }
    __syncthreads();

    // ---- R19 phase 2: gather transposed into REGISTERS (all rows, one
    // pipelined LDS exposure); invalid rows become zeros ----
    const int xg = t >> 3, c8g = (t & 7) * 8;
    union { ushort u[8]; uint4 v; } gt0[3], gt1[3];
#pragma unroll
    for (int dy = 0; dy < 3; dy++) {
        int yy = y + dy - 1;
        if (yy >= 0 && yy < Lh) {
#pragma unroll
            for (int j = 0; j < 8; j++) {
                gt0[dy].u[j] = At [(dy * 64 + c8g + j) * 34 + xg];
                gt1[dy].u[j] = As_[(dy * 64 + c8g + j) * 34 + xg];
            }
        } else { gt0[dy].v = z; gt1[dy].v = z; }
    }
    __syncthreads();

    // ---- R19 phase 3: write final transposed layout in-place + pads ----
#pragma unroll
    for (int dy = 0; dy < 3; dy++) {
        *(uint4*)(At  + (dy * 34 + xg + 1) * 72 + c8g) = gt0[dy].v;
        *(uint4*)(As_ + (dy * 34 + xg + 1) * 72 + c8g) = gt1[dy].v;
    }
    if (t < 48) {   // zero pad columns (x=-1 and x=32)
        int dy = t / 16, rem = t % 16;
        int colp = (rem >> 3) * 33, c8p = (rem & 7) * 8;
        *(uint4*)(At + (dy * 34 + colp) * 72 + c8p) = z;
        *(uint4*)(As_ + (dy * 34 + colp) * 72 + c8p) = z;
    }

    // ---- R18(b): tap-0 W2 prefetch (issues before the barrier drain) ----
    short8 w2p[2][2];   // [cc][b0/bq]
#pragma unroll
    for (int cc = 0; cc < 2; cc++) {
        w2p[cc][0] = *(const short8*)(W2 + (size_t)(w * 32 + col) * 576 + cc * 32 + quad * 8);
        w2p[cc][1] = *(const short8*)(W2 + (size_t)(w * 32 + 16 + col) * 576 + cc * 32 + quad * 8);
    }
    __syncthreads();

    f32x4 accT[2][2] = {}, accS[2][2] = {};

    // tap 0 peeled: consumes prefetched weights
#pragma unroll
    for (int cc = 0; cc < 2; cc++) {
        int abase = (0 * 34 + col + 0) * 72 + cc * 32 + quad * 8;
        short8 aT0 = *(const short8*)(At + abase);
        short8 aT1 = *(const short8*)(At + abase + 16 * 72);
        short8 aS0 = *(const short8*)(As_ + abase);
        short8 aS1 = *(const short8*)(As_ + abase + 16 * 72);
        accT[0][0] = __builtin_amdgcn_mfma_f32_16x16x32_bf16(aT0, w2p[cc][0], accT[0][0], 0, 0, 0);
        accT[0][1] = __builtin_amdgcn_mfma_f32_16x16x32_bf16(aT0, w2p[cc][1], accT[0][1], 0, 0, 0);
        accT[1][0] = __builtin_amdgcn_mfma_f32_16x16x32_bf16(aT1, w2p[cc][0], accT[1][0], 0, 0, 0);
        accT[1][1] = __builtin_amdgcn_mfma_f32_16x16x32_bf16(aT1, w2p[cc][1], accT[1][1], 0, 0, 0);
        accS[0][0] = __builtin_amdgcn_mfma_f32_16x16x32_bf16(aS0, w2p[cc][0], accS[0][0], 0, 0, 0);
        accS[0][1] = __builtin_amdgcn_mfma_f32_16x16x32_bf16(aS0, w2p[cc][1], accS[0][1], 0, 0, 0);
        accS[1][0] = __builtin_amdgcn_mfma_f32_16x16x32_bf16(aS1, w2p[cc][0], accS[1][0], 0, 0, 0);
        accS[1][1] = __builtin_amdgcn_mfma_f32_16x16x32_bf16(aS1, w2p[cc][1], accS[1][1], 0, 0, 0);
    }

    for (int tap = 1; tap < 9; tap++) {
        int dy = tap / 3, dx = tap % 3;
#pragma unroll
        for (int cc = 0; cc < 2; cc++) {
            int kg = tap * 64 + cc * 32 + quad * 8;
            short8 b0 = *(const short8*)(W2 + (size_t)(w * 32 + col) * 576 + kg);
            short8 bq = *(const short8*)(W2 + (size_t)(w * 32 + 16 + col) * 576 + kg);
            int abase = (dy * 34 + col + dx) * 72 + cc * 32 + quad * 8;
            short8 aT0 = *(const short8*)(At + abase);
            short8 aT1 = *(const short8*)(At + abase + 16 * 72);
            short8 aS0 = *(const short8*)(As_ + abase);
            short8 aS1 = *(const short8*)(As_ + abase + 16 * 72);
            accT[0][0] = __builtin_amdgcn_mfma_f32_16x16x32_bf16(aT0, b0, accT[0][0], 0, 0, 0);
            accT[0][1] = __builtin_amdgcn_mfma_f32_16x16x32_bf16(aT0, bq, accT[0][1], 0, 0, 0);
            accT[1][0] = __builtin_amdgcn_mfma_f32_16x16x32_bf16(aT1, b0, accT[1][0], 0, 0, 0);
            accT[1][1] = __builtin_amdgcn_mfma_f32_16x16x32_bf16(aT1, bq, accT[1][1], 0, 0, 0);
            accS[0][0] = __builtin_amdgcn_mfma_f32_16x16x32_bf16(aS0, b0, accS[0][0], 0, 0, 0);
            accS[0][1] = __builtin_amdgcn_mfma_f32_16x16x32_bf16(aS0, bq, accS[0][1], 0, 0, 0);
            accS[1][0] = __builtin_amdgcn_mfma_f32_16x16x32_bf16(aS1, b0, accS[1][0], 0, 0, 0);
            accS[1][1] = __builtin_amdgcn_mfma_f32_16x16x32_bf16(aS1, bq, accS[1][1], 0, 0, 0);
        }
    }

    // LN1 partial sums
#pragma unroll
    for (int mi = 0; mi < 2; mi++)
#pragma unroll
        for (int r = 0; r < 4; r++) {
            float a0 = accS[mi][0][r], a1 = accS[mi][1][r];
            float ss = a0 + a1, qq = a0 * a0 + a1 * a1;
#pragma unroll
            for (int m = 1; m < 16; m <<= 1) {
                ss += __shfl_xor(ss, m, 64);
                qq += __shfl_xor(qq, m, 64);
            }
            if (col == 0) red[mi * 16 + quad * 4 + r][w] = make_float2(ss, qq);
        }
    __syncthreads();   // also: all As_ reads done -> Xs alias becomes safe

    const float ga = g1[w * 32 + col],      ba = b1[w * 32 + col];
    const float gb = g1[w * 32 + 16 + col], bb = b1[w * 32 + 16 + col];
#pragma unroll
    for (int mi = 0; mi < 2; mi++)
#pragma unroll
        for (int r = 0; r < 4; r++) {
            int x = mi * 16 + quad * 4 + r;
            float2 p0 = red[x][0], p1 = red[x][1], p2 = red[x][2], p3 = red[x][3];
            float mean = (p0.x + p1.x + p2.x + p3.x) * (1.f / 128.f);
            float var  = (p0.y + p1.y + p2.y + p3.y) * (1.f / 128.f) - mean * mean;
            float rstd = rsqrtf(var + 1e-5f);
            int e0 = w * 32 + col, e1 = w * 32 + 16 + col;
            Xs[x * 136 + e0] = f2b((accS[mi][0][r] - mean) * rstd * ga + ba);
            Xs[x * 136 + e1] = f2b((accS[mi][1][r] - mean) * rstd * gb + bb);
            Vs[x * 136 + e0] = f2b(accT[mi][0][r]);
            Vs[x * 136 + e1] = f2b(accT[mi][1][r]);
        }

    // ---- R18(c): V-weight prefetch (issues before the barrier drain) ----
    short8 avp[2][4];
#pragma unroll
    for (int hj = 0; hj < 2; hj++)
#pragma unroll
        for (int kc = 0; kc < 4; kc++)
            avp[hj][kc] = *(const short8*)(WV + (size_t)((2 * w + hj) * 16 + col) * 128 + kc * 32 + quad * 8);
    __syncthreads();

    // phase B: QKV. Wave w -> heads 2w, 2w+1; token tiles j SEQUENTIAL
    // (register diet for the 128-reg cap at 4 blocks/CU).
    ushort* VTs = At;   // dead after MFMA loop; [8 heads][16 d][stride 34]
#pragma unroll
    for (int j = 0; j < 2; j++) {
        short8 xb[4], xv[4];
#pragma unroll
        for (int kc = 0; kc < 4; kc++) {
            xb[kc] = *(const short8*)(Xs + (j * 16 + col) * 136 + kc * 32 + quad * 8);
            xv[kc] = *(const short8*)(Vs + (j * 16 + col) * 136 + kc * 32 + quad * 8);
        }
        f32x4 Qr[2] = {}, Kr[2] = {}, Vr[2] = {};
#pragma unroll
        for (int hj = 0; hj < 2; hj++) {
            int h = 2 * w + hj;
#pragma unroll
            for (int kc = 0; kc < 4; kc++) {
                short8 aq = *(const short8*)(WQK + (size_t)(h * 16 + col) * 128 + kc * 32 + quad * 8);
                short8 ak = *(const short8*)(WQK + (size_t)(128 + h * 16 + col) * 128 + kc * 32 + quad * 8);
                Qr[hj] = __builtin_amdgcn_mfma_f32_16x16x32_bf16(aq, xb[kc], Qr[hj], 0, 0, 0);
                Kr[hj] = __builtin_amdgcn_mfma_f32_16x16x32_bf16(ak, xb[kc], Kr[hj], 0, 0, 0);
                Vr[hj] = __builtin_amdgcn_mfma_f32_16x16x32_bf16(avp[hj][kc], xv[kc], Vr[hj], 0, 0, 0);
            }
        }
#pragma unroll
        for (int hj = 0; hj < 2; hj++) {
            int h = 2 * w + hj;
            int l = y * 32 + j * 16 + col;
            size_t base = ((size_t)(n * 8 + h) * 1024 + l) * 16 + quad * 4;
            ushort4 oq, ok;
            oq.x = f2b(Qr[hj][0]); oq.y = f2b(Qr[hj][1]); oq.z = f2b(Qr[hj][2]); oq.w = f2b(Qr[hj][3]);
            ok.x = f2b(Kr[hj][0]); ok.y = f2b(Kr[hj][1]); ok.z = f2b(Kr[hj][2]); ok.w = f2b(Kr[hj][3]);
            *(ushort4*)(Qh + base) = oq;
            *(ushort4*)(Kh + base) = ok;
            int xp = ((col >> 2) << 3) + (j << 2) + (col & 3);
#pragma unroll
            for (int r = 0; r < 4; r++)
                VTs[(h * 16 + quad * 4 + r) * 34 + xp] = f2b(Vr[hj][r]);
        }
    }
#pragma unroll
    for (int k = 0; k < 2; k++) {
        int idx2 = t + k * 256;
        int r = idx2 >> 4, seg = idx2 & 15;
        *(uint4*)(TOKb + ((size_t)((y * 32 + r) * 25 + n)) * 128 + seg * 8) =
            *(const uint4*)(Vs + r * 136 + seg * 8);
    }
    __syncthreads();
    {   // coalesced VTg write
        int h = t >> 5, rem = t & 31, d = rem >> 1, xh = (rem & 1) * 16;
        size_t vrow = ((size_t)(n * 8 + h) * 32 + y) * 512;
        union { ushort u[8]; uint4 v; } o0, o1;
#pragma unroll
        for (int j = 0; j < 8; j++) {
            o0.u[j] = VTs[(h * 16 + d) * 34 + xh + j];
            o1.u[j] = VTs[(h * 16 + d) * 34 + xh + 8 + j];
        }
        *(uint4*)(VTg + vrow + d * 32 + xh)     = o0.v;
        *(uint4*)(VTg + vrow + d * 32 + xh + 8) = o1.v;
    }
}

// ---------------------------------------------------------------------------
// Attention + out_proj + residual + LN2 + FFN + conv, fully fused.
// Grid 800 (n,y), 32 tokens/block. R17: register diet — no w2pp prefetch;
// ffn2 residual via MFMA C-in (Y2 init = Y, Y dies at ffn2 entry). FROZEN.
// ---------------------------------------------------------------------------
__global__ __launch_bounds__(256, 4) void k_attn_ffn(
    const ushort* __restrict__ Qh, const ushort* __restrict__ Kh,
    const ushort* __restrict__ VTg, const ushort* __restrict__ WOP,
    const float* __restrict__ g2, const float* __restrict__ b2,
    const ushort* __restrict__ W1, const ushort* __restrict__ W2P,
    const ushort* __restrict__ WCP, const ushort* __restrict__ TOKb,
    float* __restrict__ out)
{
    __shared__ ushort OX[32 * 136];
    __shared__ ushort Rs[32 * 136];   // residual; later aliased as Ys
    __shared__ ushort Hs[32 * 264];
    __shared__ float2 red[32][4];
    ushort* Ys = Rs;                  // Rs dead 2 barriers before Ys write
    const int bid = blockIdx.x;                       // 800 blocks
    const int idx = (bid & 7) * 100 + (bid >> 3);     // XCD-contiguous chunks
    const int n = idx / 32, y = idx & 31;
    const int t = threadIdx.x, w = t >> 6, lane = t & 63;
    const int col = lane & 15, quad = lane >> 4;

    {   // stage residual rows (32 tokens, bf16)
#pragma unroll
        for (int k = 0; k < 2; k++) {
            int idx2 = t + k * 256;
            int r = idx2 >> 4, seg = idx2 & 15;
            *(uint4*)(Rs + r * 136 + seg * 8) =
                *(const uint4*)(TOKb + ((size_t)((y * 32 + r) * 25 + n)) * 128 + seg * 8);
        }
    }

    short8 z8 = {0, 0, 0, 0, 0, 0, 0, 0};
    const size_t base0 = (size_t)(n * 8 + 2 * w) * 1024;
    const size_t base1 = base0 + 1024;
    const size_t vbase0 = (size_t)(n * 8 + 2 * w) * 32 * 512;
    const size_t vbase1 = vbase0 + 32 * 512;

    short8 wop[2][4];   // out_proj weights, prefetched during half-1 attention

    // ================= attention, half = 0, 1 =================
#pragma unroll
    for (int half = 0; half < 2; half++) {
        const int qx = half * 16 + col;
        unsigned long long mbits = 0;
#pragma unroll
        for (int tt = 0; tt < 10; tt++) {
            int yy = y - 2 + (tt >> 1);
            bool rok = (yy >= 0) && (yy < 32);
            int kxb = ((tt & 1) << 4) + quad * 4;
#pragma unroll
            for (int r = 0; r < 4; r++) {
                int dd = kxb + r - qx;
                if (rok && ((unsigned)(dd + 2) <= 4u))
                    mbits |= 1ull << (tt * 4 + r);
            }
        }

        short8 qf0 = z8, qf1 = z8;
        if (quad < 2) {
            qf0 = *(const short8*)(Qh + (base0 + y * 32 + half * 16 + col) * 16 + quad * 8);
            qf1 = *(const short8*)(Qh + (base1 + y * 32 + half * 16 + col) * 16 + quad * 8);
        }

        // scores + exp + bf16 pack per y-row (packed-P diet)
        union { ushort u[8]; short8 s; } pb0[5], pb1[5];
        float sum0 = 0.f, sum1 = 0.f;
#pragma unroll
        for (int kr = 0; kr < 5; kr++) {
            int yyc = min(max(y - 2 + kr, 0), 31);
            short8 kf0a = z8, kf0b = z8, kf1a = z8, kf1b = z8;
            if (quad < 2) {
                kf0a = *(const short8*)(Kh + (base0 + yyc * 32 + col) * 16 + quad * 8);
                kf0b = *(const short8*)(Kh + (base0 + yyc * 32 + 16 + col) * 16 + quad * 8);
                kf1a = *(const short8*)(Kh + (base1 + yyc * 32 + col) * 16 + quad * 8);
                kf1b = *(const short8*)(Kh + (base1 + yyc * 32 + 16 + col) * 16 + quad * 8);
            }
            f32x4 S00 = {}, S01 = {}, S10 = {}, S11 = {};
            S00 = __builtin_amdgcn_mfma_f32_16x16x32_bf16(kf0a, qf0, S00, 0, 0, 0);
            S01 = __builtin_amdgcn_mfma_f32_16x16x32_bf16(kf0b, qf0, S01, 0, 0, 0);
            S10 = __builtin_amdgcn_mfma_f32_16x16x32_bf16(kf1a, qf1, S10, 0, 0, 0);
            S11 = __builtin_amdgcn_mfma_f32_16x16x32_bf16(kf1b, qf1, S11, 0, 0, 0);
#pragma unroll
            for (int i = 0; i < 8; i++) {
                int tt = 2 * kr + (i >> 2), r = i & 3;
                bool ok = (mbits >> (tt * 4 + r)) & 1;
                float s0 = (i >= 4) ? S01[r] : S00[r];
                float s1 = (i >= 4) ? S11[r] : S10[r];
                float p0 = ok ? __expf(s0) : 0.f;
                float p1 = ok ? __expf(s1) : 0.f;
                pb0[kr].u[i] = f2b(p0);
                pb1[kr].u[i] = f2b(p1);
                sum0 += p0; sum1 += p1;
            }
        }
        sum0 += __shfl_xor(sum0, 16, 64); sum0 += __shfl_xor(sum0, 32, 64);
        sum1 += __shfl_xor(sum1, 16, 64); sum1 += __shfl_xor(sum1, 32, 64);
        const float inv0 = 1.f / sum0, inv1 = 1.f / sum1;

        // prefetch out_proj weights during half-1 PV (latency hidden by
        // PV MFMAs + the barrier's straggler wait)
        if (half == 1) {
#pragma unroll
            for (int jj = 0; jj < 2; jj++)
#pragma unroll
                for (int kc = 0; kc < 4; kc++)
                    wop[jj][kc] = *(const short8*)(WOP + (size_t)((2 * w + jj) * 16 + col) * 128 + kc * 32 + quad * 8);
        }

        // PV: A-frags from VTg (half-independent addresses; L1-hot in half 1)
        f32x4 O20 = {}, O21 = {};
#pragma unroll
        for (int c = 0; c < 5; c++) {
            int yyc = min(max(y - 2 + c, 0), 31);
            short8 vt0 = *(const short8*)(VTg + vbase0 + (size_t)yyc * 512 + col * 32 + quad * 8);
            short8 vt1 = *(const short8*)(VTg + vbase1 + (size_t)yyc * 512 + col * 32 + quad * 8);
            O20 = __builtin_amdgcn_mfma_f32_16x16x32_bf16(vt0, pb0[c].s, O20, 0, 0, 0);
            O21 = __builtin_amdgcn_mfma_f32_16x16x32_bf16(vt1, pb1[c].s, O21, 0, 0, 0);
        }
#pragma unroll
        for (int r = 0; r < 4; r++) { O20[r] *= inv0; O21[r] *= inv1; }

        // pack O (heads 2w,2w+1) -> OX rows half*16+col, B-operand k-slice w
        union { ushort u[8]; uint4 v; } pk;
#pragma unroll
        for (int i = 0; i < 4; i++) { pk.u[i] = f2b(O20[i]); pk.u[4 + i] = f2b(O21[i]); }
        *(uint4*)(OX + (half * 16 + col) * 136 + w * 32 + quad * 8) = pk.v;
    }
    __syncthreads();

    // ================= out_proj: 32 tokens, wave w -> e-tiles {2w,2w+1} ====
    f32x4 Y[2][2] = {};   // [jj][token tile]
#pragma unroll
    for (int kc = 0; kc < 4; kc++) {
        short8 hb0 = *(const short8*)(OX + col * 136 + kc * 32 + quad * 8);
        short8 hb1 = *(const short8*)(OX + (16 + col) * 136 + kc * 32 + quad * 8);
#pragma unroll
        for (int jj = 0; jj < 2; jj++) {
            Y[jj][0] = __builtin_amdgcn_mfma_f32_16x16x32_bf16(wop[jj][kc], hb0, Y[jj][0], 0, 0, 0);
            Y[jj][1] = __builtin_amdgcn_mfma_f32_16x16x32_bf16(wop[jj][kc], hb1, Y[jj][1], 0, 0, 0);
        }
    }

    // PREFETCH W1 first half (ft = 4w, 4w+1) under out_proj/LN2
    short8 w1p[2][4];
#pragma unroll
    for (int j2 = 0; j2 < 2; j2++)
#pragma unroll
        for (int kc = 0; kc < 4; kc++)
            w1p[j2][kc] = *(const short8*)(W1 + (size_t)((4 * w + j2) * 16 + col) * 128 + kc * 32 + quad * 8);

    // residual + LN2 stats (token = tt*16+col)
#pragma unroll
    for (int tt = 0; tt < 2; tt++) {
        float sum = 0.f, sq = 0.f;
#pragma unroll
        for (int jj = 0; jj < 2; jj++)
#pragma unroll
            for (int r = 0; r < 4; r++) {
                int e = (2 * w + jj) * 16 + quad * 4 + r;
                float v = Y[jj][tt][r] + b2f(Rs[(tt * 16 + col) * 136 + e]);
                Y[jj][tt][r] = v;
                sum += v; sq += v * v;
            }
        sum += __shfl_xor(sum, 16, 64); sum += __shfl_xor(sum, 32, 64);
        sq  += __shfl_xor(sq, 16, 64);  sq  += __shfl_xor(sq, 32, 64);
        if (quad == 0) red[tt * 16 + col][w] = make_float2(sum, sq);
    }
    __syncthreads();

#pragma unroll
    for (int tt = 0; tt < 2; tt++) {
        int tok = tt * 16 + col;
        float2 p0 = red[tok][0], p1 = red[tok][1], p2 = red[tok][2], p3 = red[tok][3];
        float mean = (p0.x + p1.x + p2.x + p3.x) * (1.f / 128.f);
        float var  = (p0.y + p1.y + p2.y + p3.y) * (1.f / 128.f) - mean * mean;
        float rstd = rsqrtf(var + 1e-5f);
#pragma unroll
        for (int jj = 0; jj < 2; jj++)
#pragma unroll
            for (int r = 0; r < 4; r++) {
                int e = (2 * w + jj) * 16 + quad * 4 + r;
                OX[tok * 136 + e] = f2b((Y[jj][tt][r] - mean) * rstd * g2[e] + b2[e]);
            }
    }
    __syncthreads();

    // ================= ffn1: ft = 4w..4w+3, both token tiles ===============
#pragma unroll
    for (int tt = 0; tt < 2; tt++) {
        short8 xb[4];
#pragma unroll
        for (int kc = 0; kc < 4; kc++)
            xb[kc] = *(const short8*)(OX + (tt * 16 + col) * 136 + kc * 32 + quad * 8);
        f32x4 H[4] = {};
#pragma unroll
        for (int j = 0; j < 4; j++) {
#pragma unroll
            for (int kc = 0; kc < 4; kc++) {
                short8 a = (j < 2) ? w1p[j][kc]
                         : *(const short8*)(W1 + (size_t)((4 * w + j) * 16 + col) * 128 + kc * 32 + quad * 8);
                H[j] = __builtin_amdgcn_mfma_f32_16x16x32_bf16(a, xb[kc], H[j], 0, 0, 0);
            }
        }
#pragma unroll
        for (int cc = 0; cc < 2; cc++) {
            union { ushort u[8]; uint4 v; } pk;
#pragma unroll
            for (int i = 0; i < 8; i++)
                pk.u[i] = f2b(fmaxf(H[2 * cc + (i >> 2)][i & 3], 0.f));
            *(uint4*)(Hs + (tt * 16 + col) * 264 + (2 * w + cc) * 32 + quad * 8) = pk.v;
        }
    }
    __syncthreads();

    // ================= ffn2: et = 2w,2w+1 over K=256, both token tiles =====
    // Residual as MFMA C-in: Y2 starts from Y -> Y dies here (reg diet).
    f32x4 Y2[2][2];
#pragma unroll
    for (int j = 0; j < 2; j++) {
        Y2[j][0] = Y[j][0];
        Y2[j][1] = Y[j][1];
    }
#pragma unroll
    for (int kc = 0; kc < 8; kc++) {
        short8 hb0 = *(const short8*)(Hs + col * 264 + kc * 32 + quad * 8);
        short8 hb1 = *(const short8*)(Hs + (16 + col) * 264 + kc * 32 + quad * 8);
#pragma unroll
        for (int j = 0; j < 2; j++) {
            short8 a = *(const short8*)(W2P + (size_t)((2 * w + j) * 16 + col) * 256 + kc * 32 + quad * 8);
            Y2[j][0] = __builtin_amdgcn_mfma_f32_16x16x32_bf16(a, hb0, Y2[j][0], 0, 0, 0);
            Y2[j][1] = __builtin_amdgcn_mfma_f32_16x16x32_bf16(a, hb1, Y2[j][1], 0, 0, 0);
        }
    }

    // PREFETCH conv weights under ffn2 tail
    short8 wcp[4];
#pragma unroll
    for (int c = 0; c < 4; c++)
        wcp[c] = *(const short8*)(WCP + (size_t)(w * 16 + col) * 128 + c * 32 + quad * 8);

#pragma unroll
    for (int tt = 0; tt < 2; tt++) {
        union { ushort u[8]; uint4 v; } pk;
#pragma unroll
        for (int i = 0; i < 8; i++)
            pk.u[i] = f2b(Y2[i >> 2][tt][i & 3]);
        *(uint4*)(Ys + (tt * 16 + col) * 136 + w * 32 + quad * 8) = pk.v;
    }
    __syncthreads();

    // ================= conv, ot = w, both token tiles ======================
    f32x4 O[2] = {};
#pragma unroll
    for (int c = 0; c < 4; c++) {
        short8 yb0 = *(const short8*)(Ys + col * 136 + c * 32 + quad * 8);
        short8 yb1 = *(const short8*)(Ys + (16 + col) * 136 + c * 32 + quad * 8);
        O[0] = __builtin_amdgcn_mfma_f32_16x16x32_bf16(wcp[c], yb0, O[0], 0, 0, 0);
        O[1] = __builtin_amdgcn_mfma_f32_16x16x32_bf16(wcp[c], yb1, O[1], 0, 0, 0);
    }
#pragma unroll
    for (int tt = 0; tt < 2; tt++) {
        int l = y * 32 + tt * 16 + col;
#pragma unroll
        for (int r2 = 0; r2 < 4; r2++) {
            int o = w * 16 + quad * 4 + r2;
            out[(size_t)(o * 25 + n) * 1024 + l] = O[tt][r2];
        }
    }
}

// ---------------------------------------------------------------------------
// Launch
// ---------------------------------------------------------------------------
extern "C" void kernel_launch(void* const* d_in, const int* in_sizes, int n_in,
                              void* d_out, int out_size, void* d_ws, size_t ws_size,
                              hipStream_t stream)
{
    const float* buffer   = (const float*)d_in[0];
    const float* spa      = (const float*)d_in[1];
    const float* w_mlp    = (const float*)d_in[2];
    const float* ln1_g    = (const float*)d_in[3];
    const float* ln1_b    = (const float*)d_in[4];
    const float* in_proj  = (const float*)d_in[5];
    const float* out_proj = (const float*)d_in[6];
    const float* ln2_g    = (const float*)d_in[7];
    const float* ln2_b    = (const float*)d_in[8];
    const float* ff_w1    = (const float*)d_in[9];
    const float* ff_w2    = (const float*)d_in[10];
    const float* conv_w   = (const float*)d_in[11];
    float* out = (float*)d_out;

    char* ws = (char*)d_ws;
    ushort* TOKb = (ushort*)(ws);                //  6,553,600 residual bf16
    ushort* Qh   = (ushort*)(ws + 6553600);      //  6,553,600 [n][h][l][d]
    ushort* Kh   = (ushort*)(ws + 13107200);     //  6,553,600
    ushort* VTg  = (ushort*)(ws + 19660800);     //  6,553,600 [n][h][y][d][xp]
    ushort* Wb   = (ushort*)(ws + 26214400);     //    425,984

    k_prep<<<dim3((W_TOTAL + 255) / 256), 256, 0, stream>>>(
        w_mlp, in_proj, out_proj, ff_w1, ff_w2, conv_w, Wb);
    k_tok_qkv<<<dim3(800), 256, 0, stream>>>(buffer, spa, Wb + OFF_W2,
                                             Wb + OFF_WQK, Wb + OFF_WV,
                                             ln1_g, ln1_b, TOKb, Qh, Kh, VTg);
    k_attn_ffn<<<dim3(800), 256, 0, stream>>>(Qh, Kh, VTg, Wb + OFF_WO,
                                              ln2_g, ln2_b, Wb + OFF_W1,
                                              Wb + OFF_W2F, Wb + OFF_WC,
                                              TOKb, out);
}

// Round 10
// 163.391 us; speedup vs baseline: 1.0110x; 1.0110x over previous
//
#include <hip/hip_runtime.h>
#include <math.h>

// SpaTrans on MI355X. R20: software-pipelined tap loop in k_tok_qkv.
//  * R19b post-mortem: barrier-collapse real but small (47.8->46.3avg);
//    VGPR_Count 56/128 shows the compiler keeps almost nothing in flight.
//    The tap loop (8 rolled iters x 2cc, 2 W2 global loads each feeding
//    that iter's MFMAs) exposes ~16 L2 latencies (~2.4-4k cyc) between
//    two block-wide barriers.
//  * R20: iteration-ahead weight prefetch — tap-1 weights loaded into
//    nb[2][2] before the prologue barrier (with tap-0's w2p); each loop
//    iter rotates nb->current and issues tap+1's loads BEFORE the MFMAs.
//    Peak regs ~80 < 128 budget.
//  * k_attn_ffn (R17 de-spilled) / k_prep frozen.
//    Tripwire: WRITE_SIZE stays 25600KB / FETCH ~7.6MB (spill shows first).
#define Lh 32
#define Lw 32
#define LL 1024
#define BN 25
#define EE 128
#define CC 64
#define NHD 8
#define DH 16
#define FFD 256
#define MROWS 25600

typedef __attribute__((ext_vector_type(8))) short short8;
typedef __attribute__((ext_vector_type(4))) float f32x4;

__device__ inline ushort f2b(float x) {
    union { float f; unsigned u; } v; v.f = x;
    unsigned r = (v.u + 0x7fffu + ((v.u >> 16) & 1u)) >> 16;
    return (ushort)r;
}
__device__ inline float b2f(ushort u) {
    union { unsigned u; float f; } v; v.u = ((unsigned)u) << 16;
    return v.f;
}

// ---------------------------------------------------------------------------
// Weight layout (ushorts). W2 K-reordered (k'=tap*64+ch). WO/W2F/WC k-PERMUTED
// (kpos=c*32+q*8+i <-> orig k=(2c+(i>>2))*16+q*4+(i&3)). Q rows pre-scaled 0.25.
// ---------------------------------------------------------------------------
#define OFF_W2  0
#define OFF_WQK 73728
#define OFF_WV  106496
#define OFF_WO  122880
#define OFF_W1  139264
#define OFF_W2F 172032
#define OFF_WC  204800
#define W_TOTAL 212992

__global__ __launch_bounds__(256) void k_prep(
    const float* __restrict__ w_mlp, const float* __restrict__ in_proj,
    const float* __restrict__ out_proj, const float* __restrict__ ff_w1,
    const float* __restrict__ ff_w2, const float* __restrict__ conv_w,
    ushort* __restrict__ Wb)
{
    int i = blockIdx.x * 256 + threadIdx.x;
    if (i >= W_TOTAL) return;
    if (i < 73728) {
        int e = i / 576, k = i - e * 576;
        int tap = k >> 6, ch = k & 63;
        Wb[OFF_W2 + i] = f2b(w_mlp[e * 576 + ch * 9 + tap]);
        return;
    }
    i -= 73728;
    if (i < 32768) {   // WQK; Q rows pre-scaled by 1/sqrt(16)
        float v = in_proj[i];
        Wb[OFF_WQK + i] = f2b(i < 16384 ? v * 0.25f : v);
        return;
    }
    i -= 32768;
    if (i < 16384) { Wb[OFF_WV + i] = f2b(in_proj[32768 + i]); return; }
    i -= 16384;
    if (i < 16384) {   // WO, k-permuted (K=128)
        int e = i >> 7, kpos = i & 127;
        int c = kpos >> 5, q = (kpos >> 3) & 3, ii = kpos & 7;
        int orig = (2 * c + (ii >> 2)) * 16 + q * 4 + (ii & 3);
        Wb[OFF_WO + i] = f2b(out_proj[e * 128 + orig]);
        return;
    }
    i -= 16384;
    if (i < 32768) { Wb[OFF_W1 + i] = f2b(ff_w1[i]); return; }
    i -= 32768;
    if (i < 32768) {   // W2F, k-permuted (K=256)
        int e = i >> 8, kpos = i & 255;
        int c = kpos >> 5, q = (kpos >> 3) & 3, ii = kpos & 7;
        int orig = (2 * c + (ii >> 2)) * 16 + q * 4 + (ii & 3);
        Wb[OFF_W2F + i] = f2b(ff_w2[e * 256 + orig]);
        return;
    }
    i -= 32768;
    {                  // WC, k-permuted (K=128)
        int o = i >> 7, kpos = i & 127;
        int c = kpos >> 5, q = (kpos >> 3) & 3, ii = kpos & 7;
        int orig = (2 * c + (ii >> 2)) * 16 + q * 4 + (ii & 3);
        Wb[OFF_WC + i] = f2b(conv_w[o * 128 + orig]);
    }
}

// ---------------------------------------------------------------------------
// Token embed + LN1 + QKV, input transpose fused. Grid 800.
// R16: LDS 39.1KB -> 4 blocks/CU, single generation.
// R19: single-pass in-place transpose (3 barriers, regs as pivot).
// R20: tap loop software-pipelined (tap+1 weights prefetched under tap).
// ---------------------------------------------------------------------------
__global__ __launch_bounds__(256, 4) void k_tok_qkv(
    const float* __restrict__ buf, const float* __restrict__ spa,
    const ushort* __restrict__ W2, const ushort* __restrict__ WQK,
    const ushort* __restrict__ WV, const float* __restrict__ g1,
    const float* __restrict__ b1, ushort* __restrict__ TOKb,
    ushort* __restrict__ Qh, ushort* __restrict__ Kh, ushort* __restrict__ VTg)
{
    const int bid = blockIdx.x;                       // 800 blocks
    const int idx = (bid & 7) * 100 + (bid >> 3);     // XCD-contiguous chunks
    const int n = idx / 32, y = idx & 31;
    __shared__ ushort At[3 * 34 * 72];
    __shared__ ushort As_[3 * 34 * 72];
    __shared__ ushort VsBuf[32 * 136];
    __shared__ float2 red[32][4];
    ushort* Xs  = As_;               // alias: As_ dead after tap loop
    ushort* Vs  = VsBuf;
    const int t = threadIdx.x;
    const int w = t >> 6, lane = t & 63;
    const int col = lane & 15, quad = lane >> 4;
    const uint4 z = make_uint4(0, 0, 0, 0);

    // ---- R19 phase 1: load all 3 rows, pack bf16, stage UNTRANSPOSED
    // into At/As_ ([dy][ch][stride 34]; 13056B < 14688B region) ----
    {
        const int ch = t >> 2, x8 = (t & 3) * 8;
#pragma unroll
        for (int dy = 0; dy < 3; dy++) {
            int yy = y + dy - 1;
            if (yy >= 0 && yy < Lh) {
                const float* p = buf + ((size_t)(ch * BN + n) * LL + yy * Lw + x8);
                const float* q = spa + ((size_t)(ch * BN + n) * LL + yy * Lw + x8);
                float4 a0 = ((const float4*)p)[0], a1 = ((const float4*)p)[1];
                float4 b0 = ((const float4*)q)[0], b1 = ((const float4*)q)[1];
                union { ushort u[8]; uint w4[4]; } o0, o1;
                o0.u[0] = f2b(a0.x); o0.u[1] = f2b(a0.y); o0.u[2] = f2b(a0.z); o0.u[3] = f2b(a0.w);
                o0.u[4] = f2b(a1.x); o0.u[5] = f2b(a1.y); o0.u[6] = f2b(a1.z); o0.u[7] = f2b(a1.w);
                o1.u[0] = f2b(a0.x + b0.x); o1.u[1] = f2b(a0.y + b0.y);
                o1.u[2] = f2b(a0.z + b0.z); o1.u[3] = f2b(a0.w + b0.w);
                o1.u[4] = f2b(a1.x + b1.x); o1.u[5] = f2b(a1.y + b1.y);
                o1.u[6] = f2b(a1.z + b1.z); o1.u[7] = f2b(a1.w + b1.w);
                uint* d0 = (uint*)(At  + (dy * 64 + ch) * 34 + x8);
                uint* d1 = (uint*)(As_ + (dy * 64 + ch) * 34 + x8);
#pragma unroll
                for (int k = 0; k < 4; k++) { d0[k] = o0.w4[k]; d1[k] = o1.w4[k]; }
            }
        }
    }
    __syncthreads();

    // ---- R19 phase 2: gather transposed into REGISTERS (all rows, one
    // pipelined LDS exposure); invalid rows become zeros ----
    const int xg = t >> 3, c8g = (t & 7) * 8;
    union { ushort u[8]; uint4 v; } gt0[3], gt1[3];
#pragma unroll
    for (int dy = 0; dy < 3; dy++) {
        int yy = y + dy - 1;
        if (yy >= 0 && yy < Lh) {
#pragma unroll
            for (int j = 0; j < 8; j++) {
                gt0[dy].u[j] = At [(dy * 64 + c8g + j) * 34 + xg];
                gt1[dy].u[j] = As_[(dy * 64 + c8g + j) * 34 + xg];
            }
        } else { gt0[dy].v = z; gt1[dy].v = z; }
    }
    __syncthreads();

    // ---- R19 phase 3: write final transposed layout in-place + pads ----
#pragma unroll
    for (int dy = 0; dy < 3; dy++) {
        *(uint4*)(At  + (dy * 34 + xg + 1) * 72 + c8g) = gt0[dy].v;
        *(uint4*)(As_ + (dy * 34 + xg + 1) * 72 + c8g) = gt1[dy].v;
    }
    if (t < 48) {   // zero pad columns (x=-1 and x=32)
        int dy = t / 16, rem = t % 16;
        int colp = (rem >> 3) * 33, c8p = (rem & 7) * 8;
        *(uint4*)(At + (dy * 34 + colp) * 72 + c8p) = z;
        *(uint4*)(As_ + (dy * 34 + colp) * 72 + c8p) = z;
    }

    // ---- R18(b)+R20: tap-0 AND tap-1 W2 prefetch (issue before drain) ----
    short8 w2p[2][2];   // tap 0: [cc][b0/bq]
#pragma unroll
    for (int cc = 0; cc < 2; cc++) {
        w2p[cc][0] = *(const short8*)(W2 + (size_t)(w * 32 + col) * 576 + cc * 32 + quad * 8);
        w2p[cc][1] = *(const short8*)(W2 + (size_t)(w * 32 + 16 + col) * 576 + cc * 32 + quad * 8);
    }
    short8 nb[2][2];    // tap 1 (rotates through the loop)
#pragma unroll
    for (int cc = 0; cc < 2; cc++) {
        nb[cc][0] = *(const short8*)(W2 + (size_t)(w * 32 + col) * 576 + 64 + cc * 32 + quad * 8);
        nb[cc][1] = *(const short8*)(W2 + (size_t)(w * 32 + 16 + col) * 576 + 64 + cc * 32 + quad * 8);
    }
    __syncthreads();

    f32x4 accT[2][2] = {}, accS[2][2] = {};

    // tap 0 peeled: consumes prefetched weights
#pragma unroll
    for (int cc = 0; cc < 2; cc++) {
        int abase = (0 * 34 + col + 0) * 72 + cc * 32 + quad * 8;
        short8 aT0 = *(const short8*)(At + abase);
        short8 aT1 = *(const short8*)(At + abase + 16 * 72);
        short8 aS0 = *(const short8*)(As_ + abase);
        short8 aS1 = *(const short8*)(As_ + abase + 16 * 72);
        accT[0][0] = __builtin_amdgcn_mfma_f32_16x16x32_bf16(aT0, w2p[cc][0], accT[0][0], 0, 0, 0);
        accT[0][1] = __builtin_amdgcn_mfma_f32_16x16x32_bf16(aT0, w2p[cc][1], accT[0][1], 0, 0, 0);
        accT[1][0] = __builtin_amdgcn_mfma_f32_16x16x32_bf16(aT1, w2p[cc][0], accT[1][0], 0, 0, 0);
        accT[1][1] = __builtin_amdgcn_mfma_f32_16x16x32_bf16(aT1, w2p[cc][1], accT[1][1], 0, 0, 0);
        accS[0][0] = __builtin_amdgcn_mfma_f32_16x16x32_bf16(aS0, w2p[cc][0], accS[0][0], 0, 0, 0);
        accS[0][1] = __builtin_amdgcn_mfma_f32_16x16x32_bf16(aS0, w2p[cc][1], accS[0][1], 0, 0, 0);
        accS[1][0] = __builtin_amdgcn_mfma_f32_16x16x32_bf16(aS1, w2p[cc][0], accS[1][0], 0, 0, 0);
        accS[1][1] = __builtin_amdgcn_mfma_f32_16x16x32_bf16(aS1, w2p[cc][1], accS[1][1], 0, 0, 0);
    }

    // R20: rolled tap loop, weights one iteration ahead
    for (int tap = 1; tap < 9; tap++) {
        int dy = tap / 3, dx = tap % 3;
        short8 cb00 = nb[0][0], cb01 = nb[0][1];
        short8 cb10 = nb[1][0], cb11 = nb[1][1];
        if (tap < 8) {
            int kg = (tap + 1) * 64;
#pragma unroll
            for (int cc = 0; cc < 2; cc++) {
                nb[cc][0] = *(const short8*)(W2 + (size_t)(w * 32 + col) * 576 + kg + cc * 32 + quad * 8);
                nb[cc][1] = *(const short8*)(W2 + (size_t)(w * 32 + 16 + col) * 576 + kg + cc * 32 + quad * 8);
            }
        }
        {   // cc = 0
            int abase = (dy * 34 + col + dx) * 72 + quad * 8;
            short8 aT0 = *(const short8*)(At + abase);
            short8 aT1 = *(const short8*)(At + abase + 16 * 72);
            short8 aS0 = *(const short8*)(As_ + abase);
            short8 aS1 = *(const short8*)(As_ + abase + 16 * 72);
            accT[0][0] = __builtin_amdgcn_mfma_f32_16x16x32_bf16(aT0, cb00, accT[0][0], 0, 0, 0);
            accT[0][1] = __builtin_amdgcn_mfma_f32_16x16x32_bf16(aT0, cb01, accT[0][1], 0, 0, 0);
            accT[1][0] = __builtin_amdgcn_mfma_f32_16x16x32_bf16(aT1, cb00, accT[1][0], 0, 0, 0);
            accT[1][1] = __builtin_amdgcn_mfma_f32_16x16x32_bf16(aT1, cb01, accT[1][1], 0, 0, 0);
            accS[0][0] = __builtin_amdgcn_mfma_f32_16x16x32_bf16(aS0, cb00, accS[0][0], 0, 0, 0);
            accS[0][1] = __builtin_amdgcn_mfma_f32_16x16x32_bf16(aS0, cb01, accS[0][1], 0, 0, 0);
            accS[1][0] = __builtin_amdgcn_mfma_f32_16x16x32_bf16(aS1, cb00, accS[1][0], 0, 0, 0);
            accS[1][1] = __builtin_amdgcn_mfma_f32_16x16x32_bf16(aS1, cb01, accS[1][1], 0, 0, 0);
        }
        {   // cc = 1
            int abase = (dy * 34 + col + dx) * 72 + 32 + quad * 8;
            short8 aT0 = *(const short8*)(At + abase);
            short8 aT1 = *(const short8*)(At + abase + 16 * 72);
            short8 aS0 = *(const short8*)(As_ + abase);
            short8 aS1 = *(const short8*)(As_ + abase + 16 * 72);
            accT[0][0] = __builtin_amdgcn_mfma_f32_16x16x32_bf16(aT0, cb10, accT[0][0], 0, 0, 0);
            accT[0][1] = __builtin_amdgcn_mfma_f32_16x16x32_bf16(aT0, cb11, accT[0][1], 0, 0, 0);
            accT[1][0] = __builtin_amdgcn_mfma_f32_16x16x32_bf16(aT1, cb10, accT[1][0], 0, 0, 0);
            accT[1][1] = __builtin_amdgcn_mfma_f32_16x16x32_bf16(aT1, cb11, accT[1][1], 0, 0, 0);
            accS[0][0] = __builtin_amdgcn_mfma_f32_16x16x32_bf16(aS0, cb10, accS[0][0], 0, 0, 0);
            accS[0][1] = __builtin_amdgcn_mfma_f32_16x16x32_bf16(aS0, cb11, accS[0][1], 0, 0, 0);
            accS[1][0] = __builtin_amdgcn_mfma_f32_16x16x32_bf16(aS1, cb10, accS[1][0], 0, 0, 0);
            accS[1][1] = __builtin_amdgcn_mfma_f32_16x16x32_bf16(aS1, cb11, accS[1][1], 0, 0, 0);
        }
    }

    // LN1 partial sums
#pragma unroll
    for (int mi = 0; mi < 2; mi++)
#pragma unroll
        for (int r = 0; r < 4; r++) {
            float a0 = accS[mi][0][r], a1 = accS[mi][1][r];
            float ss = a0 + a1, qq = a0 * a0 + a1 * a1;
#pragma unroll
            for (int m = 1; m < 16; m <<= 1) {
                ss += __shfl_xor(ss, m, 64);
                qq += __shfl_xor(qq, m, 64);
            }
            if (col == 0) red[mi * 16 + quad * 4 + r][w] = make_float2(ss, qq);
        }
    __syncthreads();   // also: all As_ reads done -> Xs alias becomes safe

    const float ga = g1[w * 32 + col],      ba = b1[w * 32 + col];
    const float gb = g1[w * 32 + 16 + col], bb = b1[w * 32 + 16 + col];
#pragma unroll
    for (int mi = 0; mi < 2; mi++)
#pragma unroll
        for (int r = 0; r < 4; r++) {
            int x = mi * 16 + quad * 4 + r;
            float2 p0 = red[x][0], p1 = red[x][1], p2 = red[x][2], p3 = red[x][3];
            float mean = (p0.x + p1.x + p2.x + p3.x) * (1.f / 128.f);
            float var  = (p0.y + p1.y + p2.y + p3.y) * (1.f / 128.f) - mean * mean;
            float rstd = rsqrtf(var + 1e-5f);
            int e0 = w * 32 + col, e1 = w * 32 + 16 + col;
            Xs[x * 136 + e0] = f2b((accS[mi][0][r] - mean) * rstd * ga + ba);
            Xs[x * 136 + e1] = f2b((accS[mi][1][r] - mean) * rstd * gb + bb);
            Vs[x * 136 + e0] = f2b(accT[mi][0][r]);
            Vs[x * 136 + e1] = f2b(accT[mi][1][r]);
        }

    // ---- R18(c): V-weight prefetch (issues before the barrier drain) ----
    short8 avp[2][4];
#pragma unroll
    for (int hj = 0; hj < 2; hj++)
#pragma unroll
        for (int kc = 0; kc < 4; kc++)
            avp[hj][kc] = *(const short8*)(WV + (size_t)((2 * w + hj) * 16 + col) * 128 + kc * 32 + quad * 8);
    __syncthreads();

    // phase B: QKV. Wave w -> heads 2w, 2w+1; token tiles j SEQUENTIAL
    // (register diet for the 128-reg cap at 4 blocks/CU).
    ushort* VTs = At;   // dead after MFMA loop; [8 heads][16 d][stride 34]
#pragma unroll
    for (int j = 0; j < 2; j++) {
        short8 xb[4], xv[4];
#pragma unroll
        for (int kc = 0; kc < 4; kc++) {
            xb[kc] = *(const short8*)(Xs + (j * 16 + col) * 136 + kc * 32 + quad * 8);
            xv[kc] = *(const short8*)(Vs + (j * 16 + col) * 136 + kc * 32 + quad * 8);
        }
        f32x4 Qr[2] = {}, Kr[2] = {}, Vr[2] = {};
#pragma unroll
        for (int hj = 0; hj < 2; hj++) {
            int h = 2 * w + hj;
#pragma unroll
            for (int kc = 0; kc < 4; kc++) {
                short8 aq = *(const short8*)(WQK + (size_t)(h * 16 + col) * 128 + kc * 32 + quad * 8);
                short8 ak = *(const short8*)(WQK + (size_t)(128 + h * 16 + col) * 128 + kc * 32 + quad * 8);
                Qr[hj] = __builtin_amdgcn_mfma_f32_16x16x32_bf16(aq, xb[kc], Qr[hj], 0, 0, 0);
                Kr[hj] = __builtin_amdgcn_mfma_f32_16x16x32_bf16(ak, xb[kc], Kr[hj], 0, 0, 0);
                Vr[hj] = __builtin_amdgcn_mfma_f32_16x16x32_bf16(avp[hj][kc], xv[kc], Vr[hj], 0, 0, 0);
            }
        }
#pragma unroll
        for (int hj = 0; hj < 2; hj++) {
            int h = 2 * w + hj;
            int l = y * 32 + j * 16 + col;
            size_t base = ((size_t)(n * 8 + h) * 1024 + l) * 16 + quad * 4;
            ushort4 oq, ok;
            oq.x = f2b(Qr[hj][0]); oq.y = f2b(Qr[hj][1]); oq.z = f2b(Qr[hj][2]); oq.w = f2b(Qr[hj][3]);
            ok.x = f2b(Kr[hj][0]); ok.y = f2b(Kr[hj][1]); ok.z = f2b(Kr[hj][2]); ok.w = f2b(Kr[hj][3]);
            *(ushort4*)(Qh + base) = oq;
            *(ushort4*)(Kh + base) = ok;
            int xp = ((col >> 2) << 3) + (j << 2) + (col & 3);
#pragma unroll
            for (int r = 0; r < 4; r++)
                VTs[(h * 16 + quad * 4 + r) * 34 + xp] = f2b(Vr[hj][r]);
        }
    }
#pragma unroll
    for (int k = 0; k < 2; k++) {
        int idx2 = t + k * 256;
        int r = idx2 >> 4, seg = idx2 & 15;
        *(uint4*)(TOKb + ((size_t)((y * 32 + r) * 25 + n)) * 128 + seg * 8) =
            *(const uint4*)(Vs + r * 136 + seg * 8);
    }
    __syncthreads();
    {   // coalesced VTg write
        int h = t >> 5, rem = t & 31, d = rem >> 1, xh = (rem & 1) * 16;
        size_t vrow = ((size_t)(n * 8 + h) * 32 + y) * 512;
        union { ushort u[8]; uint4 v; } o0, o1;
#pragma unroll
        for (int j = 0; j < 8; j++) {
            o0.u[j] = VTs[(h * 16 + d) * 34 + xh + j];
            o1.u[j] = VTs[(h * 16 + d) * 34 + xh + 8 + j];
        }
        *(uint4*)(VTg + vrow + d * 32 + xh)     = o0.v;
        *(uint4*)(VTg + vrow + d * 32 + xh + 8) = o1.v;
    }
}

// ---------------------------------------------------------------------------
// Attention + out_proj + residual + LN2 + FFN + conv, fully fused.
// Grid 800 (n,y), 32 tokens/block. R17: register diet — no w2pp prefetch;
// ffn2 residual via MFMA C-in (Y2 init = Y, Y dies at ffn2 entry). FROZEN.
// ---------------------------------------------------------------------------
__global__ __launch_bounds__(256, 4) void k_attn_ffn(
    const ushort* __restrict__ Qh, const ushort* __restrict__ Kh,
    const ushort* __restrict__ VTg, const ushort* __restrict__ WOP,
    const float* __restrict__ g2, const float* __restrict__ b2,
    const ushort* __restrict__ W1, const ushort* __restrict__ W2P,
    const ushort* __restrict__ WCP, const ushort* __restrict__ TOKb,
    float* __restrict__ out)
{
    __shared__ ushort OX[32 * 136];
    __shared__ ushort Rs[32 * 136];   // residual; later aliased as Ys
    __shared__ ushort Hs[32 * 264];
    __shared__ float2 red[32][4];
    ushort* Ys = Rs;                  // Rs dead 2 barriers before Ys write
    const int bid = blockIdx.x;                       // 800 blocks
    const int idx = (bid & 7) * 100 + (bid >> 3);     // XCD-contiguous chunks
    const int n = idx / 32, y = idx & 31;
    const int t = threadIdx.x, w = t >> 6, lane = t & 63;
    const int col = lane & 15, quad = lane >> 4;

    {   // stage residual rows (32 tokens, bf16)
#pragma unroll
        for (int k = 0; k < 2; k++) {
            int idx2 = t + k * 256;
            int r = idx2 >> 4, seg = idx2 & 15;
            *(uint4*)(Rs + r * 136 + seg * 8) =
                *(const uint4*)(TOKb + ((size_t)((y * 32 + r) * 25 + n)) * 128 + seg * 8);
        }
    }

    short8 z8 = {0, 0, 0, 0, 0, 0, 0, 0};
    const size_t base0 = (size_t)(n * 8 + 2 * w) * 1024;
    const size_t base1 = base0 + 1024;
    const size_t vbase0 = (size_t)(n * 8 + 2 * w) * 32 * 512;
    const size_t vbase1 = vbase0 + 32 * 512;

    short8 wop[2][4];   // out_proj weights, prefetched during half-1 attention

    // ================= attention, half = 0, 1 =================
#pragma unroll
    for (int half = 0; half < 2; half++) {
        const int qx = half * 16 + col;
        unsigned long long mbits = 0;
#pragma unroll
        for (int tt = 0; tt < 10; tt++) {
            int yy = y - 2 + (tt >> 1);
            bool rok = (yy >= 0) && (yy < 32);
            int kxb = ((tt & 1) << 4) + quad * 4;
#pragma unroll
            for (int r = 0; r < 4; r++) {
                int dd = kxb + r - qx;
                if (rok && ((unsigned)(dd + 2) <= 4u))
                    mbits |= 1ull << (tt * 4 + r);
            }
        }

        short8 qf0 = z8, qf1 = z8;
        if (quad < 2) {
            qf0 = *(const short8*)(Qh + (base0 + y * 32 + half * 16 + col) * 16 + quad * 8);
            qf1 = *(const short8*)(Qh + (base1 + y * 32 + half * 16 + col) * 16 + quad * 8);
        }

        // scores + exp + bf16 pack per y-row (packed-P diet)
        union { ushort u[8]; short8 s; } pb0[5], pb1[5];
        float sum0 = 0.f, sum1 = 0.f;
#pragma unroll
        for (int kr = 0; kr < 5; kr++) {
            int yyc = min(max(y - 2 + kr, 0), 31);
            short8 kf0a = z8, kf0b = z8, kf1a = z8, kf1b = z8;
            if (quad < 2) {
                kf0a = *(const short8*)(Kh + (base0 + yyc * 32 + col) * 16 + quad * 8);
                kf0b = *(const short8*)(Kh + (base0 + yyc * 32 + 16 + col) * 16 + quad * 8);
                kf1a = *(const short8*)(Kh + (base1 + yyc * 32 + col) * 16 + quad * 8);
                kf1b = *(const short8*)(Kh + (base1 + yyc * 32 + 16 + col) * 16 + quad * 8);
            }
            f32x4 S00 = {}, S01 = {}, S10 = {}, S11 = {};
            S00 = __builtin_amdgcn_mfma_f32_16x16x32_bf16(kf0a, qf0, S00, 0, 0, 0);
            S01 = __builtin_amdgcn_mfma_f32_16x16x32_bf16(kf0b, qf0, S01, 0, 0, 0);
            S10 = __builtin_amdgcn_mfma_f32_16x16x32_bf16(kf1a, qf1, S10, 0, 0, 0);
            S11 = __builtin_amdgcn_mfma_f32_16x16x32_bf16(kf1b, qf1, S11, 0, 0, 0);
#pragma unroll
            for (int i = 0; i < 8; i++) {
                int tt = 2 * kr + (i >> 2), r = i & 3;
                bool ok = (mbits >> (tt * 4 + r)) & 1;
                float s0 = (i >= 4) ? S01[r] : S00[r];
                float s1 = (i >= 4) ? S11[r] : S10[r];
                float p0 = ok ? __expf(s0) : 0.f;
                float p1 = ok ? __expf(s1) : 0.f;
                pb0[kr].u[i] = f2b(p0);
                pb1[kr].u[i] = f2b(p1);
                sum0 += p0; sum1 += p1;
            }
        }
        sum0 += __shfl_xor(sum0, 16, 64); sum0 += __shfl_xor(sum0, 32, 64);
        sum1 += __shfl_xor(sum1, 16, 64); sum1 += __shfl_xor(sum1, 32, 64);
        const float inv0 = 1.f / sum0, inv1 = 1.f / sum1;

        // prefetch out_proj weights during half-1 PV (latency hidden by
        // PV MFMAs + the barrier's straggler wait)
        if (half == 1) {
#pragma unroll
            for (int jj = 0; jj < 2; jj++)
#pragma unroll
                for (int kc = 0; kc < 4; kc++)
                    wop[jj][kc] = *(const short8*)(WOP + (size_t)((2 * w + jj) * 16 + col) * 128 + kc * 32 + quad * 8);
        }

        // PV: A-frags from VTg (half-independent addresses; L1-hot in half 1)
        f32x4 O20 = {}, O21 = {};
#pragma unroll
        for (int c = 0; c < 5; c++) {
            int yyc = min(max(y - 2 + c, 0), 31);
            short8 vt0 = *(const short8*)(VTg + vbase0 + (size_t)yyc * 512 + col * 32 + quad * 8);
            short8 vt1 = *(const short8*)(VTg + vbase1 + (size_t)yyc * 512 + col * 32 + quad * 8);
            O20 = __builtin_amdgcn_mfma_f32_16x16x32_bf16(vt0, pb0[c].s, O20, 0, 0, 0);
            O21 = __builtin_amdgcn_mfma_f32_16x16x32_bf16(vt1, pb1[c].s, O21, 0, 0, 0);
        }
#pragma unroll
        for (int r = 0; r < 4; r++) { O20[r] *= inv0; O21[r] *= inv1; }

        // pack O (heads 2w,2w+1) -> OX rows half*16+col, B-operand k-slice w
        union { ushort u[8]; uint4 v; } pk;
#pragma unroll
        for (int i = 0; i < 4; i++) { pk.u[i] = f2b(O20[i]); pk.u[4 + i] = f2b(O21[i]); }
        *(uint4*)(OX + (half * 16 + col) * 136 + w * 32 + quad * 8) = pk.v;
    }
    __syncthreads();

    // ================= out_proj: 32 tokens, wave w -> e-tiles {2w,2w+1} ====
    f32x4 Y[2][2] = {};   // [jj][token tile]
#pragma unroll
    for (int kc = 0; kc < 4; kc++) {
        short8 hb0 = *(const short8*)(OX + col * 136 + kc * 32 + quad * 8);
        short8 hb1 = *(const short8*)(OX + (16 + col) * 136 + kc * 32 + quad * 8);
#pragma unroll
        for (int jj = 0; jj < 2; jj++) {
            Y[jj][0] = __builtin_amdgcn_mfma_f32_16x16x32_bf16(wop[jj][kc], hb0, Y[jj][0], 0, 0, 0);
            Y[jj][1] = __builtin_amdgcn_mfma_f32_16x16x32_bf16(wop[jj][kc], hb1, Y[jj][1], 0, 0, 0);
        }
    }

    // PREFETCH W1 first half (ft = 4w, 4w+1) under out_proj/LN2
    short8 w1p[2][4];
#pragma unroll
    for (int j2 = 0; j2 < 2; j2++)
#pragma unroll
        for (int kc = 0; kc < 4; kc++)
            w1p[j2][kc] = *(const short8*)(W1 + (size_t)((4 * w + j2) * 16 + col) * 128 + kc * 32 + quad * 8);

    // residual + LN2 stats (token = tt*16+col)
#pragma unroll
    for (int tt = 0; tt < 2; tt++) {
        float sum = 0.f, sq = 0.f;
#pragma unroll
        for (int jj = 0; jj < 2; jj++)
#pragma unroll
            for (int r = 0; r < 4; r++) {
                int e = (2 * w + jj) * 16 + quad * 4 + r;
                float v = Y[jj][tt][r] + b2f(Rs[(tt * 16 + col) * 136 + e]);
                Y[jj][tt][r] = v;
                sum += v; sq += v * v;
            }
        sum += __shfl_xor(sum, 16, 64); sum += __shfl_xor(sum, 32, 64);
        sq  += __shfl_xor(sq, 16, 64);  sq  += __shfl_xor(sq, 32, 64);
        if (quad == 0) red[tt * 16 + col][w] = make_float2(sum, sq);
    }
    __syncthreads();

#pragma unroll
    for (int tt = 0; tt < 2; tt++) {
        int tok = tt * 16 + col;
        float2 p0 = red[tok][0], p1 = red[tok][1], p2 = red[tok][2], p3 = red[tok][3];
        float mean = (p0.x + p1.x + p2.x + p3.x) * (1.f / 128.f);
        float var  = (p0.y + p1.y + p2.y + p3.y) * (1.f / 128.f) - mean * mean;
        float rstd = rsqrtf(var + 1e-5f);
#pragma unroll
        for (int jj = 0; jj < 2; jj++)
#pragma unroll
            for (int r = 0; r < 4; r++) {
                int e = (2 * w + jj) * 16 + quad * 4 + r;
                OX[tok * 136 + e] = f2b((Y[jj][tt][r] - mean) * rstd * g2[e] + b2[e]);
            }
    }
    __syncthreads();

    // ================= ffn1: ft = 4w..4w+3, both token tiles ===============
#pragma unroll
    for (int tt = 0; tt < 2; tt++) {
        short8 xb[4];
#pragma unroll
        for (int kc = 0; kc < 4; kc++)
            xb[kc] = *(const short8*)(OX + (tt * 16 + col) * 136 + kc * 32 + quad * 8);
        f32x4 H[4] = {};
#pragma unroll
        for (int j = 0; j < 4; j++) {
#pragma unroll
            for (int kc = 0; kc < 4; kc++) {
                short8 a = (j < 2) ? w1p[j][kc]
                         : *(const short8*)(W1 + (size_t)((4 * w + j) * 16 + col) * 128 + kc * 32 + quad * 8);
                H[j] = __builtin_amdgcn_mfma_f32_16x16x32_bf16(a, xb[kc], H[j], 0, 0, 0);
            }
        }
#pragma unroll
        for (int cc = 0; cc < 2; cc++) {
            union { ushort u[8]; uint4 v; } pk;
#pragma unroll
            for (int i = 0; i < 8; i++)
                pk.u[i] = f2b(fmaxf(H[2 * cc + (i >> 2)][i & 3], 0.f));
            *(uint4*)(Hs + (tt * 16 + col) * 264 + (2 * w + cc) * 32 + quad * 8) = pk.v;
        }
    }
    __syncthreads();

    // ================= ffn2: et = 2w,2w+1 over K=256, both token tiles =====
    // Residual as MFMA C-in: Y2 starts from Y -> Y dies here (reg diet).
    f32x4 Y2[2][2];
#pragma unroll
    for (int j = 0; j < 2; j++) {
        Y2[j][0] = Y[j][0];
        Y2[j][1] = Y[j][1];
    }
#pragma unroll
    for (int kc = 0; kc < 8; kc++) {
        short8 hb0 = *(const short8*)(Hs + col * 264 + kc * 32 + quad * 8);
        short8 hb1 = *(const short8*)(Hs + (16 + col) * 264 + kc * 32 + quad * 8);
#pragma unroll
        for (int j = 0; j < 2; j++) {
            short8 a = *(const short8*)(W2P + (size_t)((2 * w + j) * 16 + col) * 256 + kc * 32 + quad * 8);
            Y2[j][0] = __builtin_amdgcn_mfma_f32_16x16x32_bf16(a, hb0, Y2[j][0], 0, 0, 0);
            Y2[j][1] = __builtin_amdgcn_mfma_f32_16x16x32_bf16(a, hb1, Y2[j][1], 0, 0, 0);
        }
    }

    // PREFETCH conv weights under ffn2 tail
    short8 wcp[4];
#pragma unroll
    for (int c = 0; c < 4; c++)
        wcp[c] = *(const short8*)(WCP + (size_t)(w * 16 + col) * 128 + c * 32 + quad * 8);

#pragma unroll
    for (int tt = 0; tt < 2; tt++) {
        union { ushort u[8]; uint4 v; } pk;
#pragma unroll
        for (int i = 0; i < 8; i++)
            pk.u[i] = f2b(Y2[i >> 2][tt][i & 3]);
        *(uint4*)(Ys + (tt * 16 + col) * 136 + w * 32 + quad * 8) = pk.v;
    }
    __syncthreads();

    // ================= conv, ot = w, both token tiles ======================
    f32x4 O[2] = {};
#pragma unroll
    for (int c = 0; c < 4; c++) {
        short8 yb0 = *(const short8*)(Ys + col * 136 + c * 32 + quad * 8);
        short8 yb1 = *(const short8*)(Ys + (16 + col) * 136 + c * 32 + quad * 8);
        O[0] = __builtin_amdgcn_mfma_f32_16x16x32_bf16(wcp[c], yb0, O[0], 0, 0, 0);
        O[1] = __builtin_amdgcn_mfma_f32_16x16x32_bf16(wcp[c], yb1, O[1], 0, 0, 0);
    }
#pragma unroll
    for (int tt = 0; tt < 2; tt++) {
        int l = y * 32 + tt * 16 + col;
#pragma unroll
        for (int r2 = 0; r2 < 4; r2++) {
            int o = w * 16 + quad * 4 + r2;
            out[(size_t)(o * 25 + n) * 1024 + l] = O[tt][r2];
        }
    }
}

// ---------------------------------------------------------------------------
// Launch
// ---------------------------------------------------------------------------
extern "C" void kernel_launch(void* const* d_in, const int* in_sizes, int n_in,
                              void* d_out, int out_size, void* d_ws, size_t ws_size,
                              hipStream_t stream)
{
    const float* buffer   = (const float*)d_in[0];
    const float* spa      = (const float*)d_in[1];
    const float* w_mlp    = (const float*)d_in[2];
    const float* ln1_g    = (const float*)d_in[3];
    const float* ln1_b    = (const float*)d_in[4];
    const float* in_proj  = (const float*)d_in[5];
    const float* out_proj = (const float*)d_in[6];
    const float* ln2_g    = (const float*)d_in[7];
    const float* ln2_b    = (const float*)d_in[8];
    const float* ff_w1    = (const float*)d_in[9];
    const float* ff_w2    = (const float*)d_in[10];
    const float* conv_w   = (const float*)d_in[11];
    float* out = (float*)d_out;

    char* ws = (char*)d_ws;
    ushort* TOKb = (ushort*)(ws);                //  6,553,600 residual bf16
    ushort* Qh   = (ushort*)(ws + 6553600);      //  6,553,600 [n][h][l][d]
    ushort* Kh   = (ushort*)(ws + 13107200);     //  6,553,600
    ushort* VTg  = (ushort*)(ws + 19660800);     //  6,553,600 [n][h][y][d][xp]
    ushort* Wb   = (ushort*)(ws + 26214400);     //    425,984

    k_prep<<<dim3((W_TOTAL + 255) / 256), 256, 0, stream>>>(
        w_mlp, in_proj, out_proj, ff_w1, ff_w2, conv_w, Wb);
    k_tok_qkv<<<dim3(800), 256, 0, stream>>>(buffer, spa, Wb + OFF_W2,
                                             Wb + OFF_WQK, Wb + OFF_WV,
                                             ln1_g, ln1_b, TOKb, Qh, Kh, VTg);
    k_attn_ffn<<<dim3(800), 256, 0, stream>>>(Qh, Kh, VTg, Wb + OFF_WO,
                                              ln2_g, ln2_b, Wb + OFF_W1,
                                              Wb + OFF_W2F, Wb + OFF_WC,
                                              TOKb, out);
}

// Round 12
// 160.573 us; speedup vs baseline: 1.0288x; 1.0175x over previous
//
#include <hip/hip_runtime.h>
#include <math.h>

// SpaTrans on MI355X. R22: revert to R15 (empirical best: 160.4us total,
// BOTH kernels <44.2us — below the harness fill kernels).
//  * Post-R15 history: R16 tok-diet regressed tok 44->49.5 (occupancy was
//    not the lever; R13 lesson re-confirmed), R17 fixed the spill R16's
//    co-compile induced in attn, R19/R20 clawed tok back only to ~46.
//    R20 SW-pipelining: compiler sank the prefetches (VGPR stayed 56).
//    R21 cooperative fusion: correctness failure (launch-under-capture or
//    cross-XCD visibility) — not debuggable headlessly.
//  * R15 structure: 32-token blocks in k_attn_ffn (grid 800; K/V loads
//    half-independent -> shared; one FFN pipeline over 32 tokens; packed-P
//    diet R13; phase-ahead weight prefetch R14). k_tok_qkv original
//    47.8KB/(256,3) version with parallel phase B.
#define Lh 32
#define Lw 32
#define LL 1024
#define BN 25
#define EE 128
#define CC 64
#define NHD 8
#define DH 16
#define FFD 256
#define MROWS 25600

typedef __attribute__((ext_vector_type(8))) short short8;
typedef __attribute__((ext_vector_type(4))) float f32x4;

__device__ inline ushort f2b(float x) {
    union { float f; unsigned u; } v; v.f = x;
    unsigned r = (v.u + 0x7fffu + ((v.u >> 16) & 1u)) >> 16;
    return (ushort)r;
}
__device__ inline float b2f(ushort u) {
    union { unsigned u; float f; } v; v.u = ((unsigned)u) << 16;
    return v.f;
}

// ---------------------------------------------------------------------------
// Weight layout (ushorts). W2 K-reordered (k'=tap*64+ch). WO/W2F/WC k-PERMUTED
// (kpos=c*32+q*8+i <-> orig k=(2c+(i>>2))*16+q*4+(i&3)). Q rows pre-scaled 0.25.
// ---------------------------------------------------------------------------
#define OFF_W2  0
#define OFF_WQK 73728
#define OFF_WV  106496
#define OFF_WO  122880
#define OFF_W1  139264
#define OFF_W2F 172032
#define OFF_WC  204800
#define W_TOTAL 212992

__global__ __launch_bounds__(256) void k_prep(
    const float* __restrict__ w_mlp, const float* __restrict__ in_proj,
    const float* __restrict__ out_proj, const float* __restrict__ ff_w1,
    const float* __restrict__ ff_w2, const float* __restrict__ conv_w,
    ushort* __restrict__ Wb)
{
    int i = blockIdx.x * 256 + threadIdx.x;
    if (i >= W_TOTAL) return;
    if (i < 73728) {
        int e = i / 576, k = i - e * 576;
        int tap = k >> 6, ch = k & 63;
        Wb[OFF_W2 + i] = f2b(w_mlp[e * 576 + ch * 9 + tap]);
        return;
    }
    i -= 73728;
    if (i < 32768) {   // WQK; Q rows pre-scaled by 1/sqrt(16)
        float v = in_proj[i];
        Wb[OFF_WQK + i] = f2b(i < 16384 ? v * 0.25f : v);
        return;
    }
    i -= 32768;
    if (i < 16384) { Wb[OFF_WV + i] = f2b(in_proj[32768 + i]); return; }
    i -= 16384;
    if (i < 16384) {   // WO, k-permuted (K=128)
        int e = i >> 7, kpos = i & 127;
        int c = kpos >> 5, q = (kpos >> 3) & 3, ii = kpos & 7;
        int orig = (2 * c + (ii >> 2)) * 16 + q * 4 + (ii & 3);
        Wb[OFF_WO + i] = f2b(out_proj[e * 128 + orig]);
        return;
    }
    i -= 16384;
    if (i < 32768) { Wb[OFF_W1 + i] = f2b(ff_w1[i]); return; }
    i -= 32768;
    if (i < 32768) {   // W2F, k-permuted (K=256)
        int e = i >> 8, kpos = i & 255;
        int c = kpos >> 5, q = (kpos >> 3) & 3, ii = kpos & 7;
        int orig = (2 * c + (ii >> 2)) * 16 + q * 4 + (ii & 3);
        Wb[OFF_W2F + i] = f2b(ff_w2[e * 256 + orig]);
        return;
    }
    i -= 32768;
    {                  // WC, k-permuted (K=128)
        int o = i >> 7, kpos = i & 127;
        int c = kpos >> 5, q = (kpos >> 3) & 3, ii = kpos & 7;
        int orig = (2 * c + (ii >> 2)) * 16 + q * 4 + (ii & 3);
        Wb[OFF_WC + i] = f2b(conv_w[o * 128 + orig]);
    }
}

// ---------------------------------------------------------------------------
// Token embed + LN1 + QKV, input transpose fused (R10). Grid 800.
// LDS caps at 3 blocks/CU -> launch_bounds(256,3) frees VGPRs for ILP.
// ---------------------------------------------------------------------------
__global__ __launch_bounds__(256, 3) void k_tok_qkv(
    const float* __restrict__ buf, const float* __restrict__ spa,
    const ushort* __restrict__ W2, const ushort* __restrict__ WQK,
    const ushort* __restrict__ WV, const float* __restrict__ g1,
    const float* __restrict__ b1, ushort* __restrict__ TOKb,
    ushort* __restrict__ Qh, ushort* __restrict__ Kh, ushort* __restrict__ VTg)
{
    const int bid = blockIdx.x;                       // 800 blocks
    const int idx = (bid & 7) * 100 + (bid >> 3);     // XCD-contiguous chunks
    const int n = idx / 32, y = idx & 31;
    __shared__ ushort At[3 * 34 * 72];
    __shared__ ushort As_[3 * 34 * 72];
    __shared__ ushort Xs[32 * 136];   // phase A: aliased as t0 (fp32 [64][33])
    __shared__ ushort Vs[32 * 136];   // phase A: aliased as t1
    __shared__ float2 red[32][4];
    float* t0 = (float*)Xs;
    float* t1 = (float*)Vs;
    const int t = threadIdx.x;
    const uint4 z = make_uint4(0, 0, 0, 0);

    // ---- fused input transpose: 3 rows (y-1, y, y+1) ----
    for (int dy = 0; dy < 3; dy++) {
        int yy = y + dy - 1;
        if (yy >= 0 && yy < Lh) {
            {
                int ch = t >> 2, x8 = (t & 3) * 8;
                const float* p = buf + ((size_t)(ch * BN + n) * LL + yy * Lw + x8);
                const float* q = spa + ((size_t)(ch * BN + n) * LL + yy * Lw + x8);
                float4 a0 = ((const float4*)p)[0], a1 = ((const float4*)p)[1];
                float4 b0 = ((const float4*)q)[0], b1 = ((const float4*)q)[1];
                float* d0 = t0 + ch * 33 + x8;
                float* d1 = t1 + ch * 33 + x8;
                d0[0] = a0.x; d0[1] = a0.y; d0[2] = a0.z; d0[3] = a0.w;
                d0[4] = a1.x; d0[5] = a1.y; d0[6] = a1.z; d0[7] = a1.w;
                d1[0] = a0.x + b0.x; d1[1] = a0.y + b0.y; d1[2] = a0.z + b0.z; d1[3] = a0.w + b0.w;
                d1[4] = a1.x + b1.x; d1[5] = a1.y + b1.y; d1[6] = a1.z + b1.z; d1[7] = a1.w + b1.w;
            }
            __syncthreads();
            {
                int x = t >> 3, c8 = (t & 7) * 8;
                union { ushort u[8]; uint4 v; } o0, o1;
#pragma unroll
                for (int j = 0; j < 8; j++) {
                    o0.u[j] = f2b(t0[(c8 + j) * 33 + x]);
                    o1.u[j] = f2b(t1[(c8 + j) * 33 + x]);
                }
                *(uint4*)(At + (dy * 34 + x + 1) * 72 + c8) = o0.v;
                *(uint4*)(As_ + (dy * 34 + x + 1) * 72 + c8) = o1.v;
            }
            __syncthreads();
        } else {
            int x = t >> 3, c8 = (t & 7) * 8;
            *(uint4*)(At + (dy * 34 + x + 1) * 72 + c8) = z;
            *(uint4*)(As_ + (dy * 34 + x + 1) * 72 + c8) = z;
        }
    }
    if (t < 48) {   // zero pad columns (x=-1 and x=32)
        int dy = t / 16, rem = t % 16;
        int colp = (rem >> 3) * 33, c8p = (rem & 7) * 8;
        *(uint4*)(At + (dy * 34 + colp) * 72 + c8p) = z;
        *(uint4*)(As_ + (dy * 34 + colp) * 72 + c8p) = z;
    }
    __syncthreads();

    const int w = t >> 6, lane = t & 63;
    const int col = lane & 15, quad = lane >> 4;
    f32x4 accT[2][2] = {}, accS[2][2] = {};

    for (int tap = 0; tap < 9; tap++) {
        int dy = tap / 3, dx = tap % 3;
#pragma unroll
        for (int cc = 0; cc < 2; cc++) {
            int kg = tap * 64 + cc * 32 + quad * 8;
            short8 b0 = *(const short8*)(W2 + (size_t)(w * 32 + col) * 576 + kg);
            short8 bq = *(const short8*)(W2 + (size_t)(w * 32 + 16 + col) * 576 + kg);
            int abase = (dy * 34 + col + dx) * 72 + cc * 32 + quad * 8;
            short8 aT0 = *(const short8*)(At + abase);
            short8 aT1 = *(const short8*)(At + abase + 16 * 72);
            short8 aS0 = *(const short8*)(As_ + abase);
            short8 aS1 = *(const short8*)(As_ + abase + 16 * 72);
            accT[0][0] = __builtin_amdgcn_mfma_f32_16x16x32_bf16(aT0, b0, accT[0][0], 0, 0, 0);
            accT[0][1] = __builtin_amdgcn_mfma_f32_16x16x32_bf16(aT0, bq, accT[0][1], 0, 0, 0);
            accT[1][0] = __builtin_amdgcn_mfma_f32_16x16x32_bf16(aT1, b0, accT[1][0], 0, 0, 0);
            accT[1][1] = __builtin_amdgcn_mfma_f32_16x16x32_bf16(aT1, bq, accT[1][1], 0, 0, 0);
            accS[0][0] = __builtin_amdgcn_mfma_f32_16x16x32_bf16(aS0, b0, accS[0][0], 0, 0, 0);
            accS[0][1] = __builtin_amdgcn_mfma_f32_16x16x32_bf16(aS0, bq, accS[0][1], 0, 0, 0);
            accS[1][0] = __builtin_amdgcn_mfma_f32_16x16x32_bf16(aS1, b0, accS[1][0], 0, 0, 0);
            accS[1][1] = __builtin_amdgcn_mfma_f32_16x16x32_bf16(aS1, bq, accS[1][1], 0, 0, 0);
        }
    }

    // LN1 partial sums
#pragma unroll
    for (int mi = 0; mi < 2; mi++)
#pragma unroll
        for (int r = 0; r < 4; r++) {
            float a0 = accS[mi][0][r], a1 = accS[mi][1][r];
            float ss = a0 + a1, qq = a0 * a0 + a1 * a1;
#pragma unroll
            for (int m = 1; m < 16; m <<= 1) {
                ss += __shfl_xor(ss, m, 64);
                qq += __shfl_xor(qq, m, 64);
            }
            if (col == 0) red[mi * 16 + quad * 4 + r][w] = make_float2(ss, qq);
        }
    __syncthreads();

    const float ga = g1[w * 32 + col],      ba = b1[w * 32 + col];
    const float gb = g1[w * 32 + 16 + col], bb = b1[w * 32 + 16 + col];
#pragma unroll
    for (int mi = 0; mi < 2; mi++)
#pragma unroll
        for (int r = 0; r < 4; r++) {
            int x = mi * 16 + quad * 4 + r;
            float2 p0 = red[x][0], p1 = red[x][1], p2 = red[x][2], p3 = red[x][3];
            float mean = (p0.x + p1.x + p2.x + p3.x) * (1.f / 128.f);
            float var  = (p0.y + p1.y + p2.y + p3.y) * (1.f / 128.f) - mean * mean;
            float rstd = rsqrtf(var + 1e-5f);
            int e0 = w * 32 + col, e1 = w * 32 + 16 + col;
            Xs[x * 136 + e0] = f2b((accS[mi][0][r] - mean) * rstd * ga + ba);
            Xs[x * 136 + e1] = f2b((accS[mi][1][r] - mean) * rstd * gb + bb);
            Vs[x * 136 + e0] = f2b(accT[mi][0][r]);
            Vs[x * 136 + e1] = f2b(accT[mi][1][r]);
        }
    __syncthreads();

    // phase B: QKV. Wave w -> heads 2w, 2w+1; token tiles j=0,1.
    short8 xb[2][4], xv[2][4];
#pragma unroll
    for (int j = 0; j < 2; j++)
#pragma unroll
        for (int kc = 0; kc < 4; kc++) {
            xb[j][kc] = *(const short8*)(Xs + (j * 16 + col) * 136 + kc * 32 + quad * 8);
            xv[j][kc] = *(const short8*)(Vs + (j * 16 + col) * 136 + kc * 32 + quad * 8);
        }
    f32x4 Q[2][2] = {}, K[2][2] = {}, V[2][2] = {};
#pragma unroll
    for (int hj = 0; hj < 2; hj++) {
        int h = 2 * w + hj;
#pragma unroll
        for (int kc = 0; kc < 4; kc++) {
            short8 aq = *(const short8*)(WQK + (size_t)(h * 16 + col) * 128 + kc * 32 + quad * 8);
            short8 ak = *(const short8*)(WQK + (size_t)(128 + h * 16 + col) * 128 + kc * 32 + quad * 8);
            short8 av = *(const short8*)(WV + (size_t)(h * 16 + col) * 128 + kc * 32 + quad * 8);
#pragma unroll
            for (int j = 0; j < 2; j++) {
                Q[hj][j] = __builtin_amdgcn_mfma_f32_16x16x32_bf16(aq, xb[j][kc], Q[hj][j], 0, 0, 0);
                K[hj][j] = __builtin_amdgcn_mfma_f32_16x16x32_bf16(ak, xb[j][kc], K[hj][j], 0, 0, 0);
                V[hj][j] = __builtin_amdgcn_mfma_f32_16x16x32_bf16(av, xv[j][kc], V[hj][j], 0, 0, 0);
            }
        }
    }
    ushort* VTs = At;   // dead after MFMA loop; [8 heads][16 d][stride 34]
#pragma unroll
    for (int hj = 0; hj < 2; hj++) {
        int h = 2 * w + hj;
#pragma unroll
        for (int j = 0; j < 2; j++) {
            int l = y * 32 + j * 16 + col;
            size_t base = ((size_t)(n * 8 + h) * 1024 + l) * 16 + quad * 4;
            ushort4 oq, ok;
            oq.x = f2b(Q[hj][j][0]); oq.y = f2b(Q[hj][j][1]); oq.z = f2b(Q[hj][j][2]); oq.w = f2b(Q[hj][j][3]);
            ok.x = f2b(K[hj][j][0]); ok.y = f2b(K[hj][j][1]); ok.z = f2b(K[hj][j][2]); ok.w = f2b(K[hj][j][3]);
            *(ushort4*)(Qh + base) = oq;
            *(ushort4*)(Kh + base) = ok;
            int xp = ((col >> 2) << 3) + (j << 2) + (col & 3);
#pragma unroll
            for (int r = 0; r < 4; r++)
                VTs[(h * 16 + quad * 4 + r) * 34 + xp] = f2b(V[hj][j][r]);
        }
    }
#pragma unroll
    for (int k = 0; k < 2; k++) {
        int idx2 = t + k * 256;
        int r = idx2 >> 4, seg = idx2 & 15;
        *(uint4*)(TOKb + ((size_t)((y * 32 + r) * 25 + n)) * 128 + seg * 8) =
            *(const uint4*)(Vs + r * 136 + seg * 8);
    }
    __syncthreads();
    {   // coalesced VTg write
        int h = t >> 5, rem = t & 31, d = rem >> 1, xh = (rem & 1) * 16;
        size_t vrow = ((size_t)(n * 8 + h) * 32 + y) * 512;
        union { ushort u[8]; uint4 v; } o0, o1;
#pragma unroll
        for (int j = 0; j < 8; j++) {
            o0.u[j] = VTs[(h * 16 + d) * 34 + xh + j];
            o1.u[j] = VTs[(h * 16 + d) * 34 + xh + 8 + j];
        }
        *(uint4*)(VTg + vrow + d * 32 + xh)     = o0.v;
        *(uint4*)(VTg + vrow + d * 32 + xh + 8) = o1.v;
    }
}

// ---------------------------------------------------------------------------
// Attention + out_proj + residual + LN2 + FFN + conv, fully fused.
// R15: grid 800 (n,y), 32 tokens/block. Attention per half (K/V loads
// shared/L1-hot across halves), single FFN pipeline over 32 tokens.
// Ys aliased on Rs; packed-P diet (R13); phase-ahead prefetch (R14).
// ---------------------------------------------------------------------------
__global__ __launch_bounds__(256, 4) void k_attn_ffn(
    const ushort* __restrict__ Qh, const ushort* __restrict__ Kh,
    const ushort* __restrict__ VTg, const ushort* __restrict__ WOP,
    const float* __restrict__ g2, const float* __restrict__ b2,
    const ushort* __restrict__ W1, const ushort* __restrict__ W2P,
    const ushort* __restrict__ WCP, const ushort* __restrict__ TOKb,
    float* __restrict__ out)
{
    __shared__ ushort OX[32 * 136];
    __shared__ ushort Rs[32 * 136];   // residual; later aliased as Ys
    __shared__ ushort Hs[32 * 264];
    __shared__ float2 red[32][4];
    ushort* Ys = Rs;                  // Rs dead 2 barriers before Ys write
    const int bid = blockIdx.x;                       // 800 blocks
    const int idx = (bid & 7) * 100 + (bid >> 3);     // XCD-contiguous chunks
    const int n = idx / 32, y = idx & 31;
    const int t = threadIdx.x, w = t >> 6, lane = t & 63;
    const int col = lane & 15, quad = lane >> 4;

    {   // stage residual rows (32 tokens, bf16)
#pragma unroll
        for (int k = 0; k < 2; k++) {
            int idx2 = t + k * 256;
            int r = idx2 >> 4, seg = idx2 & 15;
            *(uint4*)(Rs + r * 136 + seg * 8) =
                *(const uint4*)(TOKb + ((size_t)((y * 32 + r) * 25 + n)) * 128 + seg * 8);
        }
    }

    short8 z8 = {0, 0, 0, 0, 0, 0, 0, 0};
    const size_t base0 = (size_t)(n * 8 + 2 * w) * 1024;
    const size_t base1 = base0 + 1024;
    const size_t vbase0 = (size_t)(n * 8 + 2 * w) * 32 * 512;
    const size_t vbase1 = vbase0 + 32 * 512;

    short8 wop[2][4];   // out_proj weights, prefetched during half-1 attention

    // ================= attention, half = 0, 1 =================
#pragma unroll
    for (int half = 0; half < 2; half++) {
        const int qx = half * 16 + col;
        unsigned long long mbits = 0;
#pragma unroll
        for (int tt = 0; tt < 10; tt++) {
            int yy = y - 2 + (tt >> 1);
            bool rok = (yy >= 0) && (yy < 32);
            int kxb = ((tt & 1) << 4) + quad * 4;
#pragma unroll
            for (int r = 0; r < 4; r++) {
                int dd = kxb + r - qx;
                if (rok && ((unsigned)(dd + 2) <= 4u))
                    mbits |= 1ull << (tt * 4 + r);
            }
        }

        short8 qf0 = z8, qf1 = z8;
        if (quad < 2) {
            qf0 = *(const short8*)(Qh + (base0 + y * 32 + half * 16 + col) * 16 + quad * 8);
            qf1 = *(const short8*)(Qh + (base1 + y * 32 + half * 16 + col) * 16 + quad * 8);
        }

        // scores + exp + bf16 pack per y-row (packed-P diet)
        union { ushort u[8]; short8 s; } pb0[5], pb1[5];
        float sum0 = 0.f, sum1 = 0.f;
#pragma unroll
        for (int kr = 0; kr < 5; kr++) {
            int yyc = min(max(y - 2 + kr, 0), 31);
            short8 kf0a = z8, kf0b = z8, kf1a = z8, kf1b = z8;
            if (quad < 2) {
                kf0a = *(const short8*)(Kh + (base0 + yyc * 32 + col) * 16 + quad * 8);
                kf0b = *(const short8*)(Kh + (base0 + yyc * 32 + 16 + col) * 16 + quad * 8);
                kf1a = *(const short8*)(Kh + (base1 + yyc * 32 + col) * 16 + quad * 8);
                kf1b = *(const short8*)(Kh + (base1 + yyc * 32 + 16 + col) * 16 + quad * 8);
            }
            f32x4 S00 = {}, S01 = {}, S10 = {}, S11 = {};
            S00 = __builtin_amdgcn_mfma_f32_16x16x32_bf16(kf0a, qf0, S00, 0, 0, 0);
            S01 = __builtin_amdgcn_mfma_f32_16x16x32_bf16(kf0b, qf0, S01, 0, 0, 0);
            S10 = __builtin_amdgcn_mfma_f32_16x16x32_bf16(kf1a, qf1, S10, 0, 0, 0);
            S11 = __builtin_amdgcn_mfma_f32_16x16x32_bf16(kf1b, qf1, S11, 0, 0, 0);
#pragma unroll
            for (int i = 0; i < 8; i++) {
                int tt = 2 * kr + (i >> 2), r = i & 3;
                bool ok = (mbits >> (tt * 4 + r)) & 1;
                float s0 = (i >= 4) ? S01[r] : S00[r];
                float s1 = (i >= 4) ? S11[r] : S10[r];
                float p0 = ok ? __expf(s0) : 0.f;
                float p1 = ok ? __expf(s1) : 0.f;
                pb0[kr].u[i] = f2b(p0);
                pb1[kr].u[i] = f2b(p1);
                sum0 += p0; sum1 += p1;
            }
        }
        sum0 += __shfl_xor(sum0, 16, 64); sum0 += __shfl_xor(sum0, 32, 64);
        sum1 += __shfl_xor(sum1, 16, 64); sum1 += __shfl_xor(sum1, 32, 64);
        const float inv0 = 1.f / sum0, inv1 = 1.f / sum1;

        // prefetch out_proj weights during half-1 PV (latency hidden by
        // PV MFMAs + the barrier's straggler wait)
        if (half == 1) {
#pragma unroll
            for (int jj = 0; jj < 2; jj++)
#pragma unroll
                for (int kc = 0; kc < 4; kc++)
                    wop[jj][kc] = *(const short8*)(WOP + (size_t)((2 * w + jj) * 16 + col) * 128 + kc * 32 + quad * 8);
        }

        // PV: A-frags from VTg (half-independent addresses; L1-hot in half 1)
        f32x4 O20 = {}, O21 = {};
#pragma unroll
        for (int c = 0; c < 5; c++) {
            int yyc = min(max(y - 2 + c, 0), 31);
            short8 vt0 = *(const short8*)(VTg + vbase0 + (size_t)yyc * 512 + col * 32 + quad * 8);
            short8 vt1 = *(const short8*)(VTg + vbase1 + (size_t)yyc * 512 + col * 32 + quad * 8);
            O20 = __builtin_amdgcn_mfma_f32_16x16x32_bf16(vt0, pb0[c].s, O20, 0, 0, 0);
            O21 = __builtin_amdgcn_mfma_f32_16x16x32_bf16(vt1, pb1[c].s, O21, 0, 0, 0);
        }
#pragma unroll
        for (int r = 0; r < 4; r++) { O20[r] *= inv0; O21[r] *= inv1; }

        // pack O (heads 2w,2w+1) -> OX rows half*16+col, B-operand k-slice w
        union { ushort u[8]; uint4 v; } pk;
#pragma unroll
        for (int i = 0; i < 4; i++) { pk.u[i] = f2b(O20[i]); pk.u[4 + i] = f2b(O21[i]); }
        *(uint4*)(OX + (half * 16 + col) * 136 + w * 32 + quad * 8) = pk.v;
    }
    __syncthreads();

    // ================= out_proj: 32 tokens, wave w -> e-tiles {2w,2w+1} ====
    f32x4 Y[2][2] = {};   // [jj][token tile]
#pragma unroll
    for (int kc = 0; kc < 4; kc++) {
        short8 hb0 = *(const short8*)(OX + col * 136 + kc * 32 + quad * 8);
        short8 hb1 = *(const short8*)(OX + (16 + col) * 136 + kc * 32 + quad * 8);
#pragma unroll
        for (int jj = 0; jj < 2; jj++) {
            Y[jj][0] = __builtin_amdgcn_mfma_f32_16x16x32_bf16(wop[jj][kc], hb0, Y[jj][0], 0, 0, 0);
            Y[jj][1] = __builtin_amdgcn_mfma_f32_16x16x32_bf16(wop[jj][kc], hb1, Y[jj][1], 0, 0, 0);
        }
    }

    // PREFETCH W1 first half (ft = 4w, 4w+1) under out_proj/LN2
    short8 w1p[2][4];
#pragma unroll
    for (int j2 = 0; j2 < 2; j2++)
#pragma unroll
        for (int kc = 0; kc < 4; kc++)
            w1p[j2][kc] = *(const short8*)(W1 + (size_t)((4 * w + j2) * 16 + col) * 128 + kc * 32 + quad * 8);

    // residual + LN2 stats (token = tt*16+col)
#pragma unroll
    for (int tt = 0; tt < 2; tt++) {
        float sum = 0.f, sq = 0.f;
#pragma unroll
        for (int jj = 0; jj < 2; jj++)
#pragma unroll
            for (int r = 0; r < 4; r++) {
                int e = (2 * w + jj) * 16 + quad * 4 + r;
                float v = Y[jj][tt][r] + b2f(Rs[(tt * 16 + col) * 136 + e]);
                Y[jj][tt][r] = v;
                sum += v; sq += v * v;
            }
        sum += __shfl_xor(sum, 16, 64); sum += __shfl_xor(sum, 32, 64);
        sq  += __shfl_xor(sq, 16, 64);  sq  += __shfl_xor(sq, 32, 64);
        if (quad == 0) red[tt * 16 + col][w] = make_float2(sum, sq);
    }
    __syncthreads();

#pragma unroll
    for (int tt = 0; tt < 2; tt++) {
        int tok = tt * 16 + col;
        float2 p0 = red[tok][0], p1 = red[tok][1], p2 = red[tok][2], p3 = red[tok][3];
        float mean = (p0.x + p1.x + p2.x + p3.x) * (1.f / 128.f);
        float var  = (p0.y + p1.y + p2.y + p3.y) * (1.f / 128.f) - mean * mean;
        float rstd = rsqrtf(var + 1e-5f);
#pragma unroll
        for (int jj = 0; jj < 2; jj++)
#pragma unroll
            for (int r = 0; r < 4; r++) {
                int e = (2 * w + jj) * 16 + quad * 4 + r;
                OX[tok * 136 + e] = f2b((Y[jj][tt][r] - mean) * rstd * g2[e] + b2[e]);
            }
    }
    __syncthreads();

    // ================= ffn1: ft = 4w..4w+3, both token tiles ===============
#pragma unroll
    for (int tt = 0; tt < 2; tt++) {
        short8 xb[4];
#pragma unroll
        for (int kc = 0; kc < 4; kc++)
            xb[kc] = *(const short8*)(OX + (tt * 16 + col) * 136 + kc * 32 + quad * 8);
        f32x4 H[4] = {};
#pragma unroll
        for (int j = 0; j < 4; j++) {
#pragma unroll
            for (int kc = 0; kc < 4; kc++) {
                short8 a = (j < 2) ? w1p[j][kc]
                         : *(const short8*)(W1 + (size_t)((4 * w + j) * 16 + col) * 128 + kc * 32 + quad * 8);
                H[j] = __builtin_amdgcn_mfma_f32_16x16x32_bf16(a, xb[kc], H[j], 0, 0, 0);
            }
        }
#pragma unroll
        for (int cc = 0; cc < 2; cc++) {
            union { ushort u[8]; uint4 v; } pk;
#pragma unroll
            for (int i = 0; i < 8; i++)
                pk.u[i] = f2b(fmaxf(H[2 * cc + (i >> 2)][i & 3], 0.f));
            *(uint4*)(Hs + (tt * 16 + col) * 264 + (2 * w + cc) * 32 + quad * 8) = pk.v;
        }
    }

    // PREFETCH W2P first half (kc 0..3, both et) under ffn1
    short8 w2pp[2][4];
#pragma unroll
    for (int j = 0; j < 2; j++)
#pragma unroll
        for (int kc = 0; kc < 4; kc++)
            w2pp[j][kc] = *(const short8*)(W2P + (size_t)((2 * w + j) * 16 + col) * 256 + kc * 32 + quad * 8);
    __syncthreads();

    // ================= ffn2: et = 2w,2w+1 over K=256, both token tiles =====
    f32x4 Y2[2][2] = {};
#pragma unroll
    for (int kc = 0; kc < 8; kc++) {
        short8 hb0 = *(const short8*)(Hs + col * 264 + kc * 32 + quad * 8);
        short8 hb1 = *(const short8*)(Hs + (16 + col) * 264 + kc * 32 + quad * 8);
#pragma unroll
        for (int j = 0; j < 2; j++) {
            short8 a = (kc < 4) ? w2pp[j][kc]
                     : *(const short8*)(W2P + (size_t)((2 * w + j) * 16 + col) * 256 + kc * 32 + quad * 8);
            Y2[j][0] = __builtin_amdgcn_mfma_f32_16x16x32_bf16(a, hb0, Y2[j][0], 0, 0, 0);
            Y2[j][1] = __builtin_amdgcn_mfma_f32_16x16x32_bf16(a, hb1, Y2[j][1], 0, 0, 0);
        }
    }

    // PREFETCH conv weights under ffn2 tail
    short8 wcp[4];
#pragma unroll
    for (int c = 0; c < 4; c++)
        wcp[c] = *(const short8*)(WCP + (size_t)(w * 16 + col) * 128 + c * 32 + quad * 8);

#pragma unroll
    for (int tt = 0; tt < 2; tt++) {
        union { ushort u[8]; uint4 v; } pk;
#pragma unroll
        for (int i = 0; i < 8; i++)
            pk.u[i] = f2b(Y2[i >> 2][tt][i & 3] + Y[i >> 2][tt][i & 3]);
        *(uint4*)(Ys + (tt * 16 + col) * 136 + w * 32 + quad * 8) = pk.v;
    }
    __syncthreads();

    // ================= conv, ot = w, both token tiles ======================
    f32x4 O[2] = {};
#pragma unroll
    for (int c = 0; c < 4; c++) {
        short8 yb0 = *(const short8*)(Ys + col * 136 + c * 32 + quad * 8);
        short8 yb1 = *(const short8*)(Ys + (16 + col) * 136 + c * 32 + quad * 8);
        O[0] = __builtin_amdgcn_mfma_f32_16x16x32_bf16(wcp[c], yb0, O[0], 0, 0, 0);
        O[1] = __builtin_amdgcn_mfma_f32_16x16x32_bf16(wcp[c], yb1, O[1], 0, 0, 0);
    }
#pragma unroll
    for (int tt = 0; tt < 2; tt++) {
        int l = y * 32 + tt * 16 + col;
#pragma unroll
        for (int r2 = 0; r2 < 4; r2++) {
            int o = w * 16 + quad * 4 + r2;
            out[(size_t)(o * 25 + n) * 1024 + l] = O[tt][r2];
        }
    }
}

// ---------------------------------------------------------------------------
// Launch
// ---------------------------------------------------------------------------
extern "C" void kernel_launch(void* const* d_in, const int* in_sizes, int n_in,
                              void* d_out, int out_size, void* d_ws, size_t ws_size,
                              hipStream_t stream)
{
    const float* buffer   = (const float*)d_in[0];
    const float* spa      = (const float*)d_in[1];
    const float* w_mlp    = (const float*)d_in[2];
    const float* ln1_g    = (const float*)d_in[3];
    const float* ln1_b    = (const float*)d_in[4];
    const float* in_proj  = (const float*)d_in[5];
    const float* out_proj = (const float*)d_in[6];
    const float* ln2_g    = (const float*)d_in[7];
    const float* ln2_b    = (const float*)d_in[8];
    const float* ff_w1    = (const float*)d_in[9];
    const float* ff_w2    = (const float*)d_in[10];
    const float* conv_w   = (const float*)d_in[11];
    float* out = (float*)d_out;

    char* ws = (char*)d_ws;
    ushort* TOKb = (ushort*)(ws);                //  6,553,600 residual bf16
    ushort* Qh   = (ushort*)(ws + 6553600);      //  6,553,600 [n][h][l][d]
    ushort* Kh   = (ushort*)(ws + 13107200);     //  6,553,600
    ushort* VTg  = (ushort*)(ws + 19660800);     //  6,553,600 [n][h][y][d][xp]
    ushort* Wb   = (ushort*)(ws + 26214400);     //    425,984

    k_prep<<<dim3((W_TOTAL + 255) / 256), 256, 0, stream>>>(
        w_mlp, in_proj, out_proj, ff_w1, ff_w2, conv_w, Wb);
    k_tok_qkv<<<dim3(800), 256, 0, stream>>>(buffer, spa, Wb + OFF_W2,
                                             Wb + OFF_WQK, Wb + OFF_WV,
                                             ln1_g, ln1_b, TOKb, Qh, Kh, VTg);
    k_attn_ffn<<<dim3(800), 256, 0, stream>>>(Qh, Kh, VTg, Wb + OFF_WO,
                                              ln2_g, ln2_b, Wb + OFF_W1,
                                              Wb + OFF_W2F, Wb + OFF_WC,
                                              TOKb, out);
}